// Round 3
// baseline (1571.809 us; speedup 1.0000x reference)
//
#include <hip/hip_runtime.h>
#include <stdint.h>

typedef unsigned short ushort_t;
typedef short s8v __attribute__((ext_vector_type(8)));
typedef float f4v __attribute__((ext_vector_type(4)));

#define NW 200000
#define NT 100000
#define EE 500000
#define NSEG (NT + NW + NW)   // concatenated dst slots: [tok(e_wt) | wal(e_tw) | wal(e_ww)]

__device__ __forceinline__ float b2f(unsigned short u){
  union { unsigned int i; float f; } v; v.i = ((unsigned int)u) << 16; return v.f;
}
__device__ __forceinline__ unsigned short f2b(float f){
  unsigned int x = __float_as_uint(f);
  unsigned int r = x + 0x7fffu + ((x >> 16) & 1u);   // RNE
  return (unsigned short)(r >> 16);
}
// load external float tensor element idx; fm=1 -> fp32 layout, else bf16
__device__ __forceinline__ float ldf(const void* p, long idx, int fm){
  return fm ? ((const float*)p)[idx] : b2f(((const ushort_t*)p)[idx]);
}

// ---------------- runtime dtype probes ----------------
// mode[0]: 1 = edges are int64, 0 = int32
// mode[1]: 1 = float tensors are fp32, 0 = bf16
__global__ void detect_kern(const int* ewt, const int* etw, const int* eww,
                            const unsigned* xw_words, int* mode){
  if (threadIdx.x == 0 && blockIdx.x == 0){
    unsigned o = 0;
    for (int i = 0; i < 64; ++i)
      o |= (unsigned)ewt[2 * i + 1] | (unsigned)etw[2 * i + 1] | (unsigned)eww[2 * i + 1];
    mode[0] = (o == 0) ? 1 : 0;
    // fp32 vs packed-bf16: low 16 bits of fp32 N(0,1) words are ~uniform
    // mantissa bits -> their "bf16 exponent" field is ~uniform over 0..255.
    // Real bf16 N(0,1) data has exponent in ~[90,140] (or exact +-0).
    int viol = 0;
    for (int i = 0; i < 256; ++i){
      unsigned s = xw_words[i] & 0xffffu;
      unsigned e = (s >> 7) & 0xffu;
      if (!(s == 0u || s == 0x8000u || (e >= 90u && e <= 140u))) viol++;
    }
    mode[1] = (viol > 8) ? 1 : 0;
  }
}

// ------ batched weight transpose+convert: dst[n*K+k] = bf16(src[ebase + k*N + n]) ------
struct TDesc { const void* src; ushort_t* dst; long ebase; int K; int N; };
struct TDesc8 { TDesc d[8]; };
__global__ void transpose8(TDesc8 td, const int* mode){
  int fm = mode[1];
  int mi = blockIdx.x >> 6;
  TDesc t = td.d[mi];
  int e = ((blockIdx.x & 63) << 8) + threadIdx.x;
  if (e < t.K * t.N){
    int k = e / t.N, n = e - k * t.N;
    t.dst[n * t.K + k] = f2b(ldf(t.src, t.ebase + e, fm));
  }
}

// ---------------- fold att vectors into U matvec weights ----------------
// wallet cols j: 0,1=a_s type0 (h0,h1); 2,3=a_s type2; 4,5=a_d type1; 6,7=a_d type2
// token  cols jj: 0,1=a_s type1; 2,3=a_d type0
__global__ void uprep(const void* Wsrc0, const void* Wdst0, const void* atts0, const void* attd0,
                      const void* Wsrc1, const void* Wdst1, const void* atts1, const void* attd1,
                      float* Uw0, float* Ut0, float* Uw1, float* Ut1, const int* mode){
  int fm = mode[1];
  int id = blockIdx.x * 256 + threadIdx.x;
  if (id >= (64 + 128) * 12) return;
  int layer = (id >= 64 * 12);
  int rem = layer ? id - 64 * 12 : id;
  int K = layer ? 128 : 64;
  int k = rem / 12, j = rem % 12;
  const void* Ws = layer ? Wsrc1 : Wsrc0;
  const void* Wd = layer ? Wdst1 : Wdst0;
  const void* As = layer ? atts1 : atts0;
  const void* Ad = layer ? attd1 : attd0;
  int t, h; bool src;
  if (j < 8){ const int tt[8] = {0,0,2,2,1,1,2,2}; t = tt[j]; h = j & 1; src = (j < 4); }
  else { int jj = j - 8; t = (jj < 2) ? 1 : 0; h = jj & 1; src = (jj < 2); }
  const void* W = src ? Ws : Wd;
  const void* A = src ? As : Ad;
  float acc = 0.f;
  for (int c = 0; c < 64; ++c)
    acc += ldf(W, (long)(t * K + k) * 128 + h * 64 + c, fm) * ldf(A, t * 128 + h * 64 + c, fm);
  if (j < 8) (layer ? Uw1 : Uw0)[k * 8 + j] = acc;
  else       (layer ? Ut1 : Ut0)[k * 4 + (j - 8)] = acc;
}

// ---------------- CSR build ----------------
__global__ void hist_kern(const int* ewt, const int* etw, const int* eww, const int* mode, int* deg){
  int i = blockIdx.x * 256 + threadIdx.x;
  if (i >= 3 * EE) return;
  int md = mode[0];
  int t = i / EE, e = i - t * EE;
  const int* ep = (t == 0) ? ewt : (t == 1) ? etw : eww;
  int d = md ? ep[2 * (EE + e)] : ep[EE + e];
  int base = (t == 0) ? 0 : (t == 1) ? NT : NT + NW;
  atomicAdd(&deg[base + d], 1);
}

__global__ __launch_bounds__(512) void scan1(const int* deg, int* excl, int* sums){
  __shared__ int pair[512];
  int t = threadIdx.x;
  int base = blockIdx.x * 1024;
  int i0 = base + 2 * t;
  int a = (i0 < NSEG) ? deg[i0] : 0;
  int b = (i0 + 1 < NSEG) ? deg[i0 + 1] : 0;
  int ps = a + b;
  pair[t] = ps;
  __syncthreads();
  for (int off = 1; off < 512; off <<= 1){
    int v = (t >= off) ? pair[t - off] : 0;
    __syncthreads();
    if (t >= off) pair[t] += v;
    __syncthreads();
  }
  int epair = pair[t] - ps;
  if (i0 < NSEG) excl[i0] = epair;
  if (i0 + 1 < NSEG) excl[i0 + 1] = epair + a;
  if (t == 511) sums[blockIdx.x] = pair[511];
}

__global__ __launch_bounds__(512) void scan2(int* sums, int nch){
  __shared__ int s[512];
  int t = threadIdx.x;
  int orig = (t < nch) ? sums[t] : 0;
  s[t] = orig;
  __syncthreads();
  for (int off = 1; off < 512; off <<= 1){
    int v = (t >= off) ? s[t - off] : 0;
    __syncthreads();
    if (t >= off) s[t] += v;
    __syncthreads();
  }
  if (t < nch) sums[t] = s[t] - orig;
}

__global__ void scan3(int* rowptr, int* cursor, const int* sums){
  int i = blockIdx.x * 256 + threadIdx.x;
  if (i < NSEG){
    int v = rowptr[i] + sums[i >> 10];
    rowptr[i] = v; cursor[i] = v;
  }
  if (i == 0) rowptr[NSEG] = 3 * EE;
}

__global__ void fill_kern(const int* ewt, const int* etw, const int* eww, const int* mode, int* cursor, int* adj){
  int i = blockIdx.x * 256 + threadIdx.x;
  if (i >= 3 * EE) return;
  int md = mode[0];
  int t = i / EE, e = i - t * EE;
  const int* ep = (t == 0) ? ewt : (t == 1) ? etw : eww;
  int s = md ? ep[2 * e] : ep[e];
  int d = md ? ep[2 * (EE + e)] : ep[EE + e];
  int base = (t == 0) ? 0 : (t == 1) ? NT : NT + NW;
  int pos = atomicAdd(&cursor[base + d], 1);
  adj[pos] = s;
}

// ---------------- bf16 MFMA GEMM: C[M,NC] = A[M,K] @ B[K,NC], Bt is [NC][K] bf16 ----------------
// EXTA: A is an external tensor (dtype per mode[1]); otherwise internal bf16.
template<int K, int NC, bool BIAS, bool EXTA>
__global__ __launch_bounds__(256) void gemm_kern(const void* __restrict__ A, const ushort_t* __restrict__ Bt,
                                                 const void* __restrict__ bias, ushort_t* __restrict__ C,
                                                 int M, const int* __restrict__ mode){
  __shared__ uint4 AldsR[64 * K / 8];
  __shared__ uint4 BldsR[NC * K / 8];
  ushort_t* Alds = (ushort_t*)AldsR;
  ushort_t* Blds = (ushort_t*)BldsR;
  int fm = EXTA ? mode[1] : 0;
  int tid = threadIdx.x;
  long m0 = (long)blockIdx.x * 64;
  long total = (long)M * K;
  if (EXTA && fm){
    const float* Af = (const float*)A;
    for (int ch = tid; ch < 64 * K / 8; ch += 256){
      long e = m0 * K + (long)ch * 8;
      uint4 v = make_uint4(0, 0, 0, 0);
      if (e + 8 <= total){
        const float* p = Af + e;                       // 32B aligned
        uint4 lo = *(const uint4*)p;
        uint4 hi = *(const uint4*)(p + 4);
        unsigned w0 = (unsigned)f2b(__uint_as_float(lo.x)) | ((unsigned)f2b(__uint_as_float(lo.y)) << 16);
        unsigned w1 = (unsigned)f2b(__uint_as_float(lo.z)) | ((unsigned)f2b(__uint_as_float(lo.w)) << 16);
        unsigned w2 = (unsigned)f2b(__uint_as_float(hi.x)) | ((unsigned)f2b(__uint_as_float(hi.y)) << 16);
        unsigned w3 = (unsigned)f2b(__uint_as_float(hi.z)) | ((unsigned)f2b(__uint_as_float(hi.w)) << 16);
        v = make_uint4(w0, w1, w2, w3);
      }
      AldsR[ch] = v;
    }
  } else {
    const ushort_t* Ab = (const ushort_t*)A;
    for (int ch = tid; ch < 64 * K / 8; ch += 256){
      long e = m0 * K + (long)ch * 8;
      uint4 v = make_uint4(0, 0, 0, 0);
      if (e + 8 <= total) v = *(const uint4*)(Ab + e);
      AldsR[ch] = v;
    }
  }
  for (int ch = tid; ch < NC * K / 8; ch += 256)
    BldsR[ch] = *(const uint4*)(Bt + (long)ch * 8);
  __syncthreads();
  int lane = tid & 63, wave = tid >> 6;
  int rl = lane & 15, kq = (lane >> 4) * 8;
  f4v acc[NC / 16];
#pragma unroll
  for (int i = 0; i < NC / 16; ++i) acc[i] = (f4v){0.f, 0.f, 0.f, 0.f};
  int arow = wave * 16 + rl;
#pragma unroll
  for (int kk = 0; kk < K; kk += 32){
    s8v a = *(const s8v*)(Alds + arow * K + kk + kq);
#pragma unroll
    for (int ct = 0; ct < NC / 16; ++ct){
      s8v b = *(const s8v*)(Blds + (ct * 16 + rl) * K + kk + kq);
      acc[ct] = __builtin_amdgcn_mfma_f32_16x16x32_bf16(a, b, acc[ct], 0, 0, 0);
    }
  }
  long rbase = m0 + wave * 16 + (lane >> 4) * 4;
#pragma unroll
  for (int ct = 0; ct < NC / 16; ++ct){
#pragma unroll
    for (int r = 0; r < 4; ++r){
      long gm = rbase + r;
      if (gm < M){
        float v = acc[ct][r];
        int col = ct * 16 + rl;
        if (BIAS) v += ldf(bias, col, fm);
        C[gm * NC + col] = f2b(v);
      }
    }
  }
}

// ---------------- per-node attention scalars: out[N,NCOL] = x[N,K] @ U[K,NCOL] ----------------
template<int K, int NCOL>
__global__ __launch_bounds__(256) void a_kern(const ushort_t* __restrict__ x, const float* __restrict__ U,
                                              float* __restrict__ out, int N){
  __shared__ float Ul[K * NCOL];
  int tid = threadIdx.x;
  for (int i = tid; i < K * NCOL; i += 256) Ul[i] = U[i];
  __syncthreads();
  int w = blockIdx.x * 4 + (tid >> 6);
  if (w >= N) return;
  int lane = tid & 63;
  float x0 = b2f(x[(long)w * K + lane]);
  float x1 = (K == 128) ? b2f(x[(long)w * K + 64 + lane]) : 0.f;
  float keep = 0.f;
#pragma unroll
  for (int j = 0; j < NCOL; ++j){
    float r = x0 * Ul[lane * NCOL + j];
    if (K == 128) r += x1 * Ul[(64 + lane) * NCOL + j];
#pragma unroll
    for (int off = 32; off > 0; off >>= 1) r += __shfl_xor(r, off, 64);
    if (lane == j) keep = r;
  }
  if (lane < NCOL) out[(long)w * NCOL + lane] = keep;
}

// ---------------- edge-softmax aggregation (one wave per dst node) ----------------
__device__ __forceinline__ void conv_accum(const int* __restrict__ rowptr, const int* __restrict__ adj,
    int seg_base, int d, const float* __restrict__ a_src, int src_stride, int src_col, float ad_val,
    const ushort_t* __restrict__ hs, int c0, int head, float& o0, float& o1){
  int beg = rowptr[seg_base + d], end = rowptr[seg_base + d + 1];
  if (beg >= end) return;
  float m = -1e30f;
  for (int j = beg; j < end; ++j){
    int s = adj[j];
    float a = a_src[s * src_stride + src_col + head] + ad_val;
    a = a > 0.f ? a : 0.2f * a;
    m = fmaxf(m, a);
  }
  float den = 0.f, acc0 = 0.f, acc1 = 0.f;
  for (int j = beg; j < end; ++j){
    int s = adj[j];
    float a = a_src[s * src_stride + src_col + head] + ad_val;
    a = a > 0.f ? a : 0.2f * a;
    float wgt = __expf(a - m);
    den += wgt;
    unsigned hv = *(const unsigned*)(hs + (long)s * 128 + c0);
    acc0 += wgt * b2f((unsigned short)(hv & 0xffffu));
    acc1 += wgt * b2f((unsigned short)(hv >> 16));
  }
  float inv = 1.f / (den + 1e-16f);
  o0 += acc0 * inv; o1 += acc1 * inv;
}

__global__ __launch_bounds__(256) void wallet_agg(const int* __restrict__ rowptr, const int* __restrict__ adj,
    const float* __restrict__ aw, const float* __restrict__ at,
    const ushort_t* __restrict__ hs1, const ushort_t* __restrict__ hs2,
    const void* __restrict__ bsrc, ushort_t* __restrict__ out, const int* __restrict__ mode){
  int fm = mode[1];
  int d = blockIdx.x * 4 + (threadIdx.x >> 6);
  if (d >= NW) return;
  int lane = threadIdx.x & 63;
  int head = lane >> 5, c0 = lane << 1;
  float o0 = 0.f, o1 = 0.f;
  conv_accum(rowptr, adj, NT,      d, at, 4, 0, aw[d * 8 + 4 + head], hs1, c0, head, o0, o1);
  conv_accum(rowptr, adj, NT + NW, d, aw, 8, 2, aw[d * 8 + 6 + head], hs2, c0, head, o0, o1);
  o0 += ldf(bsrc, 128 + c0, fm)     + ldf(bsrc, 256 + c0, fm);      // b[1] + b[2] rows
  o1 += ldf(bsrc, 128 + c0 + 1, fm) + ldf(bsrc, 256 + c0 + 1, fm);
  o0 = o0 > 0.f ? o0 : expm1f(o0);
  o1 = o1 > 0.f ? o1 : expm1f(o1);
  unsigned pack = (unsigned)f2b(o0) | ((unsigned)f2b(o1) << 16);
  *(unsigned*)(out + (long)d * 128 + c0) = pack;
}

__global__ __launch_bounds__(256) void token_agg(const int* __restrict__ rowptr, const int* __restrict__ adj,
    const float* __restrict__ aw, const float* __restrict__ at, const ushort_t* __restrict__ hs0,
    const void* __restrict__ bsrc, ushort_t* __restrict__ out, const int* __restrict__ mode){
  int fm = mode[1];
  int d = blockIdx.x * 4 + (threadIdx.x >> 6);
  if (d >= NT) return;
  int lane = threadIdx.x & 63;
  int head = lane >> 5, c0 = lane << 1;
  float o0 = 0.f, o1 = 0.f;
  conv_accum(rowptr, adj, 0, d, aw, 8, 0, at[d * 4 + 2 + head], hs0, c0, head, o0, o1);
  o0 += ldf(bsrc, c0, fm);          // b[0] row
  o1 += ldf(bsrc, c0 + 1, fm);
  o0 = o0 > 0.f ? o0 : expm1f(o0);
  o1 = o1 > 0.f ? o1 : expm1f(o1);
  unsigned pack = (unsigned)f2b(o0) | ((unsigned)f2b(o1) << 16);
  *(unsigned*)(out + (long)d * 128 + c0) = pack;
}

// ---------------- classifier (dtype-aware weights + output) ----------------
__global__ __launch_bounds__(256) void cls_kern(const ushort_t* __restrict__ xw, const ushort_t* __restrict__ xt,
    const void* __restrict__ Ww, const void* __restrict__ bw,
    const void* __restrict__ Wt, const void* __restrict__ bt, void* __restrict__ out,
    const int* __restrict__ mode){
  int fm = mode[1];
  int g = blockIdx.x * 4 + (threadIdx.x >> 6);
  if (g >= NW + NT) return;
  int lane = threadIdx.x & 63;
  const ushort_t* x; const void* W; const void* b;
  if (g < NW){ x = xw + (long)g * 128; W = Ww; b = bw; }
  else { x = xt + (long)(g - NW) * 128; W = Wt; b = bt; }
  unsigned xv = *(const unsigned*)(x + 2 * lane);
  float x0 = b2f((unsigned short)(xv & 0xffffu)), x1 = b2f((unsigned short)(xv >> 16));
  float w00 = ldf(W, 4 * lane + 0, fm), w01 = ldf(W, 4 * lane + 1, fm);
  float w10 = ldf(W, 4 * lane + 2, fm), w11 = ldf(W, 4 * lane + 3, fm);
  float p0 = x0 * w00 + x1 * w10;
  float p1 = x0 * w01 + x1 * w11;
#pragma unroll
  for (int off = 32; off > 0; off >>= 1){ p0 += __shfl_xor(p0, off, 64); p1 += __shfl_xor(p1, off, 64); }
  if (lane == 0){
    float r0 = p0 + ldf(b, 0, fm);
    float r1 = p1 + ldf(b, 1, fm);
    if (fm){
      ((float*)out)[(long)g * 2]     = r0;
      ((float*)out)[(long)g * 2 + 1] = r1;
    } else {
      ((ushort_t*)out)[(long)g * 2]     = f2b(r0);
      ((ushort_t*)out)[(long)g * 2 + 1] = f2b(r1);
    }
  }
}

extern "C" void kernel_launch(void* const* d_in, const int* in_sizes, int n_in,
                              void* d_out, int out_size, void* d_ws, size_t ws_size,
                              hipStream_t stream){
  const void* x_wallet = d_in[0];
  const void* x_token  = d_in[1];
  const void* lin_w_W  = d_in[2];
  const void* lin_w_b  = d_in[3];
  const void* lin_t_W  = d_in[4];
  const void* lin_t_b  = d_in[5];
  const void* Wsrc0    = d_in[6];
  const void* Wdst0    = d_in[7];
  const void* atts0    = d_in[8];
  const void* attd0    = d_in[9];
  const void* b0       = d_in[10];
  const void* Wsrc1    = d_in[11];
  const void* Wdst1    = d_in[12];
  const void* atts1    = d_in[13];
  const void* attd1    = d_in[14];
  const void* b1       = d_in[15];
  const void* cls_w_W  = d_in[16];
  const void* cls_w_b  = d_in[17];
  const void* cls_t_W  = d_in[18];
  const void* cls_t_b  = d_in[19];
  const int* e_wt = (const int*)d_in[20];
  const int* e_tw = (const int*)d_in[21];
  const int* e_ww = (const int*)d_in[22];

  char* ws = (char*)d_ws;
  size_t off = 0;
  auto alloc = [&](size_t bytes) -> char* {
    char* p = ws + off; off += (bytes + 255) & ~(size_t)255; return p;
  };
  int* rowptr = (int*)alloc((size_t)(NSEG + 1) * 4);
  int* cursor = (int*)alloc((size_t)(NSEG + 1) * 4);
  int* deg    = (int*)alloc((size_t)NSEG * 4);
  int* adj    = (int*)alloc((size_t)3 * EE * 4);
  int* sums   = (int*)alloc(512 * 4);
  int* mode   = (int*)alloc(8);
  ushort_t* BtLw = (ushort_t*)alloc(64 * 128 * 2);
  ushort_t* BtLt = (ushort_t*)alloc(64 * 64 * 2);
  ushort_t* BtS0 = (ushort_t*)alloc(3 * 128 * 64 * 2);
  ushort_t* BtS1 = (ushort_t*)alloc(3 * 128 * 128 * 2);
  float* Uw0 = (float*)alloc(64 * 8 * 4);
  float* Ut0 = (float*)alloc(64 * 4 * 4);
  float* Uw1 = (float*)alloc(128 * 8 * 4);
  float* Ut1 = (float*)alloc(128 * 4 * 4);
  float* aw = (float*)alloc((size_t)NW * 8 * 4);
  float* at = (float*)alloc((size_t)NT * 4 * 4);
  ushort_t* hs0 = (ushort_t*)alloc((size_t)NW * 128 * 2);
  ushort_t* hs1 = (ushort_t*)alloc((size_t)NT * 128 * 2);
  ushort_t* hs2 = (ushort_t*)alloc((size_t)NW * 128 * 2);
  // x-buffer region: layer-0 hiddens (xw0,xt0) die after the L0 hs-GEMMs;
  // L0 aggregation then writes xwB/xtB into the same region (stream-ordered).
  ushort_t* xbuf = (ushort_t*)alloc(((size_t)NW + NT) * 128 * 2);
  ushort_t* xw0 = xbuf;
  ushort_t* xt0 = xbuf + (size_t)NW * 64;
  ushort_t* xwB = xbuf;                         // aliases xw0+xt0 (both dead by then)
  ushort_t* xtB = xbuf + (size_t)NW * 128;      // disjoint from xw0/xt0
  (void)in_sizes; (void)n_in;

  if (off > ws_size){
    // Workspace too small: deterministic all-zero output as a distinct signal.
    hipMemsetAsync(d_out, 0, (size_t)out_size * 2, stream);
    return;
  }

  hipMemsetAsync(deg, 0, (size_t)NSEG * 4, stream);
  detect_kern<<<1, 64, 0, stream>>>(e_wt, e_tw, e_ww, (const unsigned*)x_wallet, mode);

  TDesc8 td;
  td.d[0] = { lin_w_W, BtLw, 0, 128, 64 };
  td.d[1] = { lin_t_W, BtLt, 0, 64, 64 };
  for (int t = 0; t < 3; ++t){
    td.d[2 + t] = { Wsrc0, BtS0 + t * 128 * 64,  (long)t * 64 * 128,  64,  128 };
    td.d[5 + t] = { Wsrc1, BtS1 + t * 128 * 128, (long)t * 128 * 128, 128, 128 };
  }
  transpose8<<<512, 256, 0, stream>>>(td, mode);
  uprep<<<9, 256, 0, stream>>>(Wsrc0, Wdst0, atts0, attd0, Wsrc1, Wdst1, atts1, attd1, Uw0, Ut0, Uw1, Ut1, mode);

  int egrid = (3 * EE + 255) / 256;
  hist_kern<<<egrid, 256, 0, stream>>>(e_wt, e_tw, e_ww, mode, deg);
  int nch = (NSEG + 1023) / 1024;
  scan1<<<nch, 512, 0, stream>>>(deg, rowptr, sums);
  scan2<<<1, 512, 0, stream>>>(sums, nch);
  scan3<<<(NSEG + 255) / 256, 256, 0, stream>>>(rowptr, cursor, sums);
  fill_kern<<<egrid, 256, 0, stream>>>(e_wt, e_tw, e_ww, mode, cursor, adj);

  // input projections (external A, dtype per mode[1])
  gemm_kern<128, 64, true, true><<<NW / 64, 256, 0, stream>>>(x_wallet, BtLw, lin_w_b, xw0, NW, mode);
  gemm_kern<64, 64, true, true><<<(NT + 63) / 64, 256, 0, stream>>>(x_token, BtLt, lin_t_b, xt0, NT, mode);

  // ---- layer 0 (K=64) ----
  a_kern<64, 8><<<NW / 4, 256, 0, stream>>>(xw0, Uw0, aw, NW);
  a_kern<64, 4><<<NT / 4, 256, 0, stream>>>(xt0, Ut0, at, NT);
  gemm_kern<64, 128, false, false><<<NW / 64, 256, 0, stream>>>(xw0, BtS0, nullptr, hs0, NW, mode);
  gemm_kern<64, 128, false, false><<<(NT + 63) / 64, 256, 0, stream>>>(xt0, BtS0 + 128 * 64, nullptr, hs1, NT, mode);
  gemm_kern<64, 128, false, false><<<NW / 64, 256, 0, stream>>>(xw0, BtS0 + 2 * 128 * 64, nullptr, hs2, NW, mode);
  token_agg<<<NT / 4, 256, 0, stream>>>(rowptr, adj, aw, at, hs0, b0, xtB, mode);
  wallet_agg<<<NW / 4, 256, 0, stream>>>(rowptr, adj, aw, at, hs1, hs2, b0, xwB, mode);

  // ---- layer 1 (K=128) ----
  a_kern<128, 8><<<NW / 4, 256, 0, stream>>>(xwB, Uw1, aw, NW);
  a_kern<128, 4><<<NT / 4, 256, 0, stream>>>(xtB, Ut1, at, NT);
  gemm_kern<128, 128, false, false><<<NW / 64, 256, 0, stream>>>(xwB, BtS1, nullptr, hs0, NW, mode);
  gemm_kern<128, 128, false, false><<<(NT + 63) / 64, 256, 0, stream>>>(xtB, BtS1 + 128 * 128, nullptr, hs1, NT, mode);
  gemm_kern<128, 128, false, false><<<NW / 64, 256, 0, stream>>>(xwB, BtS1 + 2 * 128 * 128, nullptr, hs2, NW, mode);
  wallet_agg<<<NW / 4, 256, 0, stream>>>(rowptr, adj, aw, at, hs1, hs2, b1, xwB, mode);
  token_agg<<<NT / 4, 256, 0, stream>>>(rowptr, adj, aw, at, hs0, b1, xtB, mode);

  // classifier (dtype-aware output)
  cls_kern<<<(NW + NT) / 4, 256, 0, stream>>>(xwB, xtB, cls_w_W, cls_w_b, cls_t_W, cls_t_b, d_out, mode);
}

// Round 4
// 1384.403 us; speedup vs baseline: 1.1354x; 1.1354x over previous
//
#include <hip/hip_runtime.h>
#include <stdint.h>

typedef unsigned short ushort_t;
typedef short s8v __attribute__((ext_vector_type(8)));
typedef float f4v __attribute__((ext_vector_type(4)));

#define NW 200000
#define NT 100000
#define EE 500000
#define NSEG (NT + NW + NW)   // concatenated dst slots: [tok(e_wt) | wal(e_tw) | wal(e_ww)]

__device__ __forceinline__ float b2f(unsigned short u){
  union { unsigned int i; float f; } v; v.i = ((unsigned int)u) << 16; return v.f;
}
__device__ __forceinline__ unsigned short f2b(float f){
  unsigned int x = __float_as_uint(f);
  unsigned int r = x + 0x7fffu + ((x >> 16) & 1u);   // RNE
  return (unsigned short)(r >> 16);
}
__device__ __forceinline__ float ldf(const void* p, long idx, int fm){
  return fm ? ((const float*)p)[idx] : b2f(((const ushort_t*)p)[idx]);
}

// ---------------- runtime dtype probes ----------------
// mode[0]: 1 = edges are int64, 0 = int32 ; mode[1]: 1 = floats are fp32, 0 = bf16
__global__ void detect_kern(const int* ewt, const int* etw, const int* eww,
                            const unsigned* xw_words, int* mode){
  if (threadIdx.x == 0 && blockIdx.x == 0){
    unsigned o = 0;
    for (int i = 0; i < 64; ++i)
      o |= (unsigned)ewt[2 * i + 1] | (unsigned)etw[2 * i + 1] | (unsigned)eww[2 * i + 1];
    mode[0] = (o == 0) ? 1 : 0;
    int viol = 0;
    for (int i = 0; i < 256; ++i){
      unsigned s = xw_words[i] & 0xffffu;
      unsigned e = (s >> 7) & 0xffu;
      if (!(s == 0u || s == 0x8000u || (e >= 90u && e <= 140u))) viol++;
    }
    mode[1] = (viol > 8) ? 1 : 0;
  }
}

// ------ batched weight transpose+convert: dst[n*K+k] = bf16(src[ebase + k*N + n]) ------
struct TDesc { const void* src; ushort_t* dst; long ebase; int K; int N; };
struct TDesc8 { TDesc d[8]; };
__global__ void transpose8(TDesc8 td, const int* mode){
  int fm = mode[1];
  int mi = blockIdx.x >> 6;
  TDesc t = td.d[mi];
  int e = ((blockIdx.x & 63) << 8) + threadIdx.x;
  if (e < t.K * t.N){
    int k = e / t.N, n = e - k * t.N;
    t.dst[n * t.K + k] = f2b(ldf(t.src, t.ebase + e, fm));
  }
}

// ---------------- fold att vectors into U matvec weights ----------------
// wallet cols j: 0,1=a_s type0 (h0,h1); 2,3=a_s type2; 4,5=a_d type1; 6,7=a_d type2
// token  cols jj: 0,1=a_s type1; 2,3=a_d type0
__global__ void uprep(const void* Wsrc0, const void* Wdst0, const void* atts0, const void* attd0,
                      const void* Wsrc1, const void* Wdst1, const void* atts1, const void* attd1,
                      float* Uw0, float* Ut0, float* Uw1, float* Ut1, const int* mode){
  int fm = mode[1];
  int id = blockIdx.x * 256 + threadIdx.x;
  if (id >= (64 + 128) * 12) return;
  int layer = (id >= 64 * 12);
  int rem = layer ? id - 64 * 12 : id;
  int K = layer ? 128 : 64;
  int k = rem / 12, j = rem % 12;
  const void* Ws = layer ? Wsrc1 : Wsrc0;
  const void* Wd = layer ? Wdst1 : Wdst0;
  const void* As = layer ? atts1 : atts0;
  const void* Ad = layer ? attd1 : attd0;
  int t, h; bool src;
  if (j < 8){ const int tt[8] = {0,0,2,2,1,1,2,2}; t = tt[j]; h = j & 1; src = (j < 4); }
  else { int jj = j - 8; t = (jj < 2) ? 1 : 0; h = jj & 1; src = (jj < 2); }
  const void* W = src ? Ws : Wd;
  const void* A = src ? As : Ad;
  float acc = 0.f;
  for (int c = 0; c < 64; ++c)
    acc += ldf(W, (long)(t * K + k) * 128 + h * 64 + c, fm) * ldf(A, t * 128 + h * 64 + c, fm);
  if (j < 8) (layer ? Uw1 : Uw0)[k * 8 + j] = acc;
  else       (layer ? Ut1 : Ut0)[k * 4 + (j - 8)] = acc;
}

// ---------------- CSR build ----------------
__global__ void hist_kern(const int* ewt, const int* etw, const int* eww, const int* mode, int* deg){
  int i = blockIdx.x * 256 + threadIdx.x;
  if (i >= 3 * EE) return;
  int md = mode[0];
  int t = i / EE, e = i - t * EE;
  const int* ep = (t == 0) ? ewt : (t == 1) ? etw : eww;
  int d = md ? ep[2 * (EE + e)] : ep[EE + e];
  int base = (t == 0) ? 0 : (t == 1) ? NT : NT + NW;
  atomicAdd(&deg[base + d], 1);
}

__global__ __launch_bounds__(512) void scan1(const int* deg, int* excl, int* sums){
  __shared__ int pair[512];
  int t = threadIdx.x;
  int base = blockIdx.x * 1024;
  int i0 = base + 2 * t;
  int a = (i0 < NSEG) ? deg[i0] : 0;
  int b = (i0 + 1 < NSEG) ? deg[i0 + 1] : 0;
  int ps = a + b;
  pair[t] = ps;
  __syncthreads();
  for (int off = 1; off < 512; off <<= 1){
    int v = (t >= off) ? pair[t - off] : 0;
    __syncthreads();
    if (t >= off) pair[t] += v;
    __syncthreads();
  }
  int epair = pair[t] - ps;
  if (i0 < NSEG) excl[i0] = epair;
  if (i0 + 1 < NSEG) excl[i0 + 1] = epair + a;
  if (t == 511) sums[blockIdx.x] = pair[511];
}

__global__ __launch_bounds__(512) void scan2(int* sums, int nch){
  __shared__ int s[512];
  int t = threadIdx.x;
  int orig = (t < nch) ? sums[t] : 0;
  s[t] = orig;
  __syncthreads();
  for (int off = 1; off < 512; off <<= 1){
    int v = (t >= off) ? s[t - off] : 0;
    __syncthreads();
    if (t >= off) s[t] += v;
    __syncthreads();
  }
  if (t < nch) sums[t] = s[t] - orig;
}

__global__ void scan3(int* rowptr, int* cursor, const int* sums){
  int i = blockIdx.x * 256 + threadIdx.x;
  if (i < NSEG){
    int v = rowptr[i] + sums[i >> 10];
    rowptr[i] = v; cursor[i] = v;
  }
  if (i == 0) rowptr[NSEG] = 3 * EE;
}

__global__ void fill_kern(const int* ewt, const int* etw, const int* eww, const int* mode, int* cursor, int* adj){
  int i = blockIdx.x * 256 + threadIdx.x;
  if (i >= 3 * EE) return;
  int md = mode[0];
  int t = i / EE, e = i - t * EE;
  const int* ep = (t == 0) ? ewt : (t == 1) ? etw : eww;
  int s = md ? ep[2 * e] : ep[e];
  int d = md ? ep[2 * (EE + e)] : ep[EE + e];
  int base = (t == 0) ? 0 : (t == 1) ? NT : NT + NW;
  int pos = atomicAdd(&cursor[base + d], 1);
  adj[pos] = s;
}

// -------- B-stationary MFMA GEMM: C[M,NC] = A[M,K] @ Bt^T, Bt is [NC][K] bf16 --------
// B-frags live in registers for the whole kernel; each wave streams its own 32 rows
// of A directly global->VGPR->MFMA (no LDS, no barriers). Persistent grid-stride
// over 128-row chunks (4 waves x 32 rows).
template<int K, int NC, bool BIAS, bool EXTA>
__global__ __launch_bounds__(256, 2) void gemm_kern(const void* __restrict__ A, const ushort_t* __restrict__ Bt,
    const void* __restrict__ bias, ushort_t* __restrict__ C, int M,
    const int* __restrict__ mode, int nchunk){
  constexpr int CT = NC / 16, KK = K / 32;
  int fm = EXTA ? mode[1] : 0;
  int tid = threadIdx.x, lane = tid & 63, wave = tid >> 6;
  int rl = lane & 15, kq = (lane >> 4) * 8;
  s8v bfrag[CT][KK];
#pragma unroll
  for (int ct = 0; ct < CT; ++ct)
#pragma unroll
    for (int kk = 0; kk < KK; ++kk)
      bfrag[ct][kk] = *(const s8v*)(Bt + (long)(ct * 16 + rl) * K + kk * 32 + kq);
  float biasv[CT];
  if (BIAS){
#pragma unroll
    for (int ct = 0; ct < CT; ++ct) biasv[ct] = ldf(bias, ct * 16 + rl, fm);
  }
  for (int chunk = blockIdx.x; chunk < nchunk; chunk += gridDim.x){
    long m0 = (long)chunk * 128 + wave * 32;
    f4v acc[2][CT];
#pragma unroll
    for (int rt = 0; rt < 2; ++rt)
#pragma unroll
      for (int ct = 0; ct < CT; ++ct) acc[rt][ct] = (f4v){0.f, 0.f, 0.f, 0.f};
#pragma unroll
    for (int rt = 0; rt < 2; ++rt){
      long row = m0 + rt * 16 + rl;
      bool ok = row < (long)M;
#pragma unroll
      for (int kk = 0; kk < KK; ++kk){
        s8v a = (s8v){0,0,0,0,0,0,0,0};
        if (ok){
          long e = row * K + kk * 32 + kq;
          if (EXTA && fm){
            const float* p = (const float*)A + e;
            uint4 lo = *(const uint4*)p;
            uint4 hi = *(const uint4*)(p + 4);
            union { s8v v; unsigned u[4]; } t;
            t.u[0] = (unsigned)f2b(__uint_as_float(lo.x)) | ((unsigned)f2b(__uint_as_float(lo.y)) << 16);
            t.u[1] = (unsigned)f2b(__uint_as_float(lo.z)) | ((unsigned)f2b(__uint_as_float(lo.w)) << 16);
            t.u[2] = (unsigned)f2b(__uint_as_float(hi.x)) | ((unsigned)f2b(__uint_as_float(hi.y)) << 16);
            t.u[3] = (unsigned)f2b(__uint_as_float(hi.z)) | ((unsigned)f2b(__uint_as_float(hi.w)) << 16);
            a = t.v;
          } else {
            a = *(const s8v*)((const ushort_t*)A + e);
          }
        }
#pragma unroll
        for (int ct = 0; ct < CT; ++ct)
          acc[rt][ct] = __builtin_amdgcn_mfma_f32_16x16x32_bf16(a, bfrag[ct][kk], acc[rt][ct], 0, 0, 0);
      }
    }
#pragma unroll
    for (int rt = 0; rt < 2; ++rt){
      long rbase = (long)chunk * 128 + wave * 32 + rt * 16 + (lane >> 4) * 4;
#pragma unroll
      for (int ct = 0; ct < CT; ++ct){
#pragma unroll
        for (int r = 0; r < 4; ++r){
          long gm = rbase + r;
          if (gm < (long)M){
            float v = acc[rt][ct][r];
            if (BIAS) v += biasv[ct];
            C[gm * NC + ct * 16 + rl] = f2b(v);
          }
        }
      }
    }
  }
}

// ---------------- per-node attention scalars: out[N,NCOL] = x[N,K] @ U[K,NCOL] ----------------
template<int K, int NCOL>
__global__ __launch_bounds__(256) void a_kern(const ushort_t* __restrict__ x, const float* __restrict__ U,
                                              float* __restrict__ out, int N){
  __shared__ float Ul[K * NCOL];
  int tid = threadIdx.x;
  for (int i = tid; i < K * NCOL; i += 256) Ul[i] = U[i];
  __syncthreads();
  int w = blockIdx.x * 4 + (tid >> 6);
  if (w >= N) return;
  int lane = tid & 63;
  float x0 = b2f(x[(long)w * K + lane]);
  float x1 = (K == 128) ? b2f(x[(long)w * K + 64 + lane]) : 0.f;
  float keep = 0.f;
#pragma unroll
  for (int j = 0; j < NCOL; ++j){
    float r = x0 * Ul[lane * NCOL + j];
    if (K == 128) r += x1 * Ul[(64 + lane) * NCOL + j];
#pragma unroll
    for (int off = 32; off > 0; off >>= 1) r += __shfl_xor(r, off, 64);
    if (lane == j) keep = r;
  }
  if (lane < NCOL) out[(long)w * NCOL + lane] = keep;
}

// ---------------- edge-softmax aggregation (one wave per dst node) ----------------
// Lane-parallel alpha/softmax: phase 1 = one edge per lane (float2 gather covers both
// heads), wave-max; phase 2 = exp once per edge, wave-sum den, then serial
// shfl-broadcast gather (one coalesced 256B hs load per edge).
__device__ __forceinline__ void conv_fast(const int* __restrict__ rowptr, const int* __restrict__ adj,
    int seg_base, int d, const float* __restrict__ a_src, int stride, int col,
    float ad0, float ad1, const ushort_t* __restrict__ hs,
    int lane, int c0, float& o0, float& o1){
  int beg = rowptr[seg_base + d], end = rowptr[seg_base + d + 1];
  if (beg >= end) return;
  float m0 = -1e30f, m1 = -1e30f;
  float ca0 = -1e30f, ca1 = -1e30f; int cs = 0;
  for (int base = beg; base < end; base += 64){
    int j = base + lane;
    float a0 = -1e30f, a1 = -1e30f; int s = 0;
    if (j < end){
      s = adj[j];
      float2 as = *(const float2*)(a_src + (long)s * stride + col);
      a0 = as.x + ad0; a1 = as.y + ad1;
      a0 = a0 > 0.f ? a0 : 0.2f * a0;
      a1 = a1 > 0.f ? a1 : 0.2f * a1;
    }
    if (base == beg){ cs = s; ca0 = a0; ca1 = a1; }
    m0 = fmaxf(m0, a0); m1 = fmaxf(m1, a1);
  }
#pragma unroll
  for (int off = 32; off > 0; off >>= 1){
    m0 = fmaxf(m0, __shfl_xor(m0, off, 64));
    m1 = fmaxf(m1, __shfl_xor(m1, off, 64));
  }
  float den0 = 0.f, den1 = 0.f, acc0 = 0.f, acc1 = 0.f;
  for (int base = beg; base < end; base += 64){
    int j = base + lane;
    float w0 = 0.f, w1 = 0.f; int s = cs;
    if (j < end){
      float a0 = ca0, a1 = ca1;
      if (base != beg){
        s = adj[j];
        float2 as = *(const float2*)(a_src + (long)s * stride + col);
        a0 = as.x + ad0; a1 = as.y + ad1;
        a0 = a0 > 0.f ? a0 : 0.2f * a0;
        a1 = a1 > 0.f ? a1 : 0.2f * a1;
      }
      w0 = __expf(a0 - m0); w1 = __expf(a1 - m1);
    }
    den0 += w0; den1 += w1;
    int cnt = min(64, end - base);
    for (int e = 0; e < cnt; ++e){
      float we0 = __shfl(w0, e, 64);
      float we1 = __shfl(w1, e, 64);
      int ss = __shfl(s, e, 64);
      float w = (lane < 32) ? we0 : we1;
      unsigned hv = *(const unsigned*)(hs + (long)ss * 128 + c0);
      acc0 += w * b2f((unsigned short)(hv & 0xffffu));
      acc1 += w * b2f((unsigned short)(hv >> 16));
    }
  }
#pragma unroll
  for (int off = 32; off > 0; off >>= 1){
    den0 += __shfl_xor(den0, off, 64);
    den1 += __shfl_xor(den1, off, 64);
  }
  float den = (lane < 32) ? den0 : den1;
  float inv = 1.f / (den + 1e-16f);
  o0 += acc0 * inv; o1 += acc1 * inv;
}

__global__ __launch_bounds__(256) void wallet_agg(const int* __restrict__ rowptr, const int* __restrict__ adj,
    const float* __restrict__ aw, const float* __restrict__ at,
    const ushort_t* __restrict__ hs1, const ushort_t* __restrict__ hs2,
    const void* __restrict__ bsrc, ushort_t* __restrict__ out, const int* __restrict__ mode){
  int fm = mode[1];
  int d = blockIdx.x * 4 + (threadIdx.x >> 6);
  if (d >= NW) return;
  int lane = threadIdx.x & 63;
  int c0 = lane << 1;
  float2 ad1 = *(const float2*)(aw + (long)d * 8 + 4);   // a_d type1 (h0,h1)
  float2 ad2 = *(const float2*)(aw + (long)d * 8 + 6);   // a_d type2
  float o0 = 0.f, o1 = 0.f;
  conv_fast(rowptr, adj, NT,      d, at, 4, 0, ad1.x, ad1.y, hs1, lane, c0, o0, o1);
  conv_fast(rowptr, adj, NT + NW, d, aw, 8, 2, ad2.x, ad2.y, hs2, lane, c0, o0, o1);
  o0 += ldf(bsrc, 128 + c0, fm)     + ldf(bsrc, 256 + c0, fm);      // b[1] + b[2] rows
  o1 += ldf(bsrc, 128 + c0 + 1, fm) + ldf(bsrc, 256 + c0 + 1, fm);
  o0 = o0 > 0.f ? o0 : expm1f(o0);
  o1 = o1 > 0.f ? o1 : expm1f(o1);
  unsigned pack = (unsigned)f2b(o0) | ((unsigned)f2b(o1) << 16);
  *(unsigned*)(out + (long)d * 128 + c0) = pack;
}

__global__ __launch_bounds__(256) void token_agg(const int* __restrict__ rowptr, const int* __restrict__ adj,
    const float* __restrict__ aw, const float* __restrict__ at, const ushort_t* __restrict__ hs0,
    const void* __restrict__ bsrc, ushort_t* __restrict__ out, const int* __restrict__ mode){
  int fm = mode[1];
  int d = blockIdx.x * 4 + (threadIdx.x >> 6);
  if (d >= NT) return;
  int lane = threadIdx.x & 63;
  int c0 = lane << 1;
  float2 ad0 = *(const float2*)(at + (long)d * 4 + 2);   // a_d type0
  float o0 = 0.f, o1 = 0.f;
  conv_fast(rowptr, adj, 0, d, aw, 8, 0, ad0.x, ad0.y, hs0, lane, c0, o0, o1);
  o0 += ldf(bsrc, c0, fm);          // b[0] row
  o1 += ldf(bsrc, c0 + 1, fm);
  o0 = o0 > 0.f ? o0 : expm1f(o0);
  o1 = o1 > 0.f ? o1 : expm1f(o1);
  unsigned pack = (unsigned)f2b(o0) | ((unsigned)f2b(o1) << 16);
  *(unsigned*)(out + (long)d * 128 + c0) = pack;
}

// ---------------- classifier (dtype-aware weights + output) ----------------
__global__ __launch_bounds__(256) void cls_kern(const ushort_t* __restrict__ xw, const ushort_t* __restrict__ xt,
    const void* __restrict__ Ww, const void* __restrict__ bw,
    const void* __restrict__ Wt, const void* __restrict__ bt, void* __restrict__ out,
    const int* __restrict__ mode){
  int fm = mode[1];
  int g = blockIdx.x * 4 + (threadIdx.x >> 6);
  if (g >= NW + NT) return;
  int lane = threadIdx.x & 63;
  const ushort_t* x; const void* W; const void* b;
  if (g < NW){ x = xw + (long)g * 128; W = Ww; b = bw; }
  else { x = xt + (long)(g - NW) * 128; W = Wt; b = bt; }
  unsigned xv = *(const unsigned*)(x + 2 * lane);
  float x0 = b2f((unsigned short)(xv & 0xffffu)), x1 = b2f((unsigned short)(xv >> 16));
  float w00 = ldf(W, 4 * lane + 0, fm), w01 = ldf(W, 4 * lane + 1, fm);
  float w10 = ldf(W, 4 * lane + 2, fm), w11 = ldf(W, 4 * lane + 3, fm);
  float p0 = x0 * w00 + x1 * w10;
  float p1 = x0 * w01 + x1 * w11;
#pragma unroll
  for (int off = 32; off > 0; off >>= 1){ p0 += __shfl_xor(p0, off, 64); p1 += __shfl_xor(p1, off, 64); }
  if (lane == 0){
    float r0 = p0 + ldf(b, 0, fm);
    float r1 = p1 + ldf(b, 1, fm);
    if (fm){
      ((float*)out)[(long)g * 2]     = r0;
      ((float*)out)[(long)g * 2 + 1] = r1;
    } else {
      ((ushort_t*)out)[(long)g * 2]     = f2b(r0);
      ((ushort_t*)out)[(long)g * 2 + 1] = f2b(r1);
    }
  }
}

extern "C" void kernel_launch(void* const* d_in, const int* in_sizes, int n_in,
                              void* d_out, int out_size, void* d_ws, size_t ws_size,
                              hipStream_t stream){
  const void* x_wallet = d_in[0];
  const void* x_token  = d_in[1];
  const void* lin_w_W  = d_in[2];
  const void* lin_w_b  = d_in[3];
  const void* lin_t_W  = d_in[4];
  const void* lin_t_b  = d_in[5];
  const void* Wsrc0    = d_in[6];
  const void* Wdst0    = d_in[7];
  const void* atts0    = d_in[8];
  const void* attd0    = d_in[9];
  const void* b0       = d_in[10];
  const void* Wsrc1    = d_in[11];
  const void* Wdst1    = d_in[12];
  const void* atts1    = d_in[13];
  const void* attd1    = d_in[14];
  const void* b1       = d_in[15];
  const void* cls_w_W  = d_in[16];
  const void* cls_w_b  = d_in[17];
  const void* cls_t_W  = d_in[18];
  const void* cls_t_b  = d_in[19];
  const int* e_wt = (const int*)d_in[20];
  const int* e_tw = (const int*)d_in[21];
  const int* e_ww = (const int*)d_in[22];

  char* ws = (char*)d_ws;
  size_t off = 0;
  auto alloc = [&](size_t bytes) -> char* {
    char* p = ws + off; off += (bytes + 255) & ~(size_t)255; return p;
  };
  int* rowptr = (int*)alloc((size_t)(NSEG + 1) * 4);
  int* cursor = (int*)alloc((size_t)(NSEG + 1) * 4);
  int* deg    = (int*)alloc((size_t)NSEG * 4);
  int* adj    = (int*)alloc((size_t)3 * EE * 4);
  int* sums   = (int*)alloc(512 * 4);
  int* mode   = (int*)alloc(8);
  ushort_t* BtLw = (ushort_t*)alloc(64 * 128 * 2);
  ushort_t* BtLt = (ushort_t*)alloc(64 * 64 * 2);
  ushort_t* BtS0 = (ushort_t*)alloc(3 * 128 * 64 * 2);
  ushort_t* BtS1 = (ushort_t*)alloc(3 * 128 * 128 * 2);
  float* Uw0 = (float*)alloc(64 * 8 * 4);
  float* Ut0 = (float*)alloc(64 * 4 * 4);
  float* Uw1 = (float*)alloc(128 * 8 * 4);
  float* Ut1 = (float*)alloc(128 * 4 * 4);
  float* aw = (float*)alloc((size_t)NW * 8 * 4);
  float* at = (float*)alloc((size_t)NT * 4 * 4);
  ushort_t* hs0 = (ushort_t*)alloc((size_t)NW * 128 * 2);
  ushort_t* hs1 = (ushort_t*)alloc((size_t)NT * 128 * 2);
  ushort_t* hs2 = (ushort_t*)alloc((size_t)NW * 128 * 2);
  // x-buffer region: layer-0 hiddens (xw0,xt0) die after the L0 hs-GEMMs;
  // L0 aggregation then writes xwB/xtB into the same region (stream-ordered).
  ushort_t* xbuf = (ushort_t*)alloc(((size_t)NW + NT) * 128 * 2);
  ushort_t* xw0 = xbuf;
  ushort_t* xt0 = xbuf + (size_t)NW * 64;
  ushort_t* xwB = xbuf;                         // aliases xw0+xt0 (both dead by then)
  ushort_t* xtB = xbuf + (size_t)NW * 128;      // disjoint from xw0/xt0
  (void)in_sizes; (void)n_in;

  if (off > ws_size){
    hipMemsetAsync(d_out, 0, (size_t)out_size * 2, stream);
    return;
  }

  hipMemsetAsync(deg, 0, (size_t)NSEG * 4, stream);
  detect_kern<<<1, 64, 0, stream>>>(e_wt, e_tw, e_ww, (const unsigned*)x_wallet, mode);

  TDesc8 td;
  td.d[0] = { lin_w_W, BtLw, 0, 128, 64 };
  td.d[1] = { lin_t_W, BtLt, 0, 64, 64 };
  for (int t = 0; t < 3; ++t){
    td.d[2 + t] = { Wsrc0, BtS0 + t * 128 * 64,  (long)t * 64 * 128,  64,  128 };
    td.d[5 + t] = { Wsrc1, BtS1 + t * 128 * 128, (long)t * 128 * 128, 128, 128 };
  }
  transpose8<<<512, 256, 0, stream>>>(td, mode);
  uprep<<<9, 256, 0, stream>>>(Wsrc0, Wdst0, atts0, attd0, Wsrc1, Wdst1, atts1, attd1, Uw0, Ut0, Uw1, Ut1, mode);

  int egrid = (3 * EE + 255) / 256;
  hist_kern<<<egrid, 256, 0, stream>>>(e_wt, e_tw, e_ww, mode, deg);
  int nch = (NSEG + 1023) / 1024;
  scan1<<<nch, 512, 0, stream>>>(deg, rowptr, sums);
  scan2<<<1, 512, 0, stream>>>(sums, nch);
  scan3<<<(NSEG + 255) / 256, 256, 0, stream>>>(rowptr, cursor, sums);
  fill_kern<<<egrid, 256, 0, stream>>>(e_wt, e_tw, e_ww, mode, cursor, adj);

  const int G = 512;
  int ncW = (NW + 127) / 128, ncT = (NT + 127) / 128;

  // input projections (external A, dtype per mode[1])
  gemm_kern<128, 64, true, true><<<G, 256, 0, stream>>>(x_wallet, BtLw, lin_w_b, xw0, NW, mode, ncW);
  gemm_kern<64, 64, true, true><<<G, 256, 0, stream>>>(x_token, BtLt, lin_t_b, xt0, NT, mode, ncT);

  // ---- layer 0 (K=64) ----
  a_kern<64, 8><<<NW / 4, 256, 0, stream>>>(xw0, Uw0, aw, NW);
  a_kern<64, 4><<<NT / 4, 256, 0, stream>>>(xt0, Ut0, at, NT);
  gemm_kern<64, 128, false, false><<<G, 256, 0, stream>>>(xw0, BtS0, nullptr, hs0, NW, mode, ncW);
  gemm_kern<64, 128, false, false><<<G, 256, 0, stream>>>(xt0, BtS0 + 128 * 64, nullptr, hs1, NT, mode, ncT);
  gemm_kern<64, 128, false, false><<<G, 256, 0, stream>>>(xw0, BtS0 + 2 * 128 * 64, nullptr, hs2, NW, mode, ncW);
  token_agg<<<NT / 4, 256, 0, stream>>>(rowptr, adj, aw, at, hs0, b0, xtB, mode);
  wallet_agg<<<NW / 4, 256, 0, stream>>>(rowptr, adj, aw, at, hs1, hs2, b0, xwB, mode);

  // ---- layer 1 (K=128) ----
  a_kern<128, 8><<<NW / 4, 256, 0, stream>>>(xwB, Uw1, aw, NW);
  a_kern<128, 4><<<NT / 4, 256, 0, stream>>>(xtB, Ut1, at, NT);
  gemm_kern<128, 128, false, false><<<G, 256, 0, stream>>>(xwB, BtS1, nullptr, hs0, NW, mode, ncW);
  gemm_kern<128, 128, false, false><<<G, 256, 0, stream>>>(xtB, BtS1 + 128 * 128, nullptr, hs1, NT, mode, ncT);
  gemm_kern<128, 128, false, false><<<G, 256, 0, stream>>>(xwB, BtS1 + 2 * 128 * 128, nullptr, hs2, NW, mode, ncW);
  wallet_agg<<<NW / 4, 256, 0, stream>>>(rowptr, adj, aw, at, hs1, hs2, b1, xwB, mode);
  token_agg<<<NT / 4, 256, 0, stream>>>(rowptr, adj, aw, at, hs0, b1, xtB, mode);

  // classifier (dtype-aware output)
  cls_kern<<<(NW + NT) / 4, 256, 0, stream>>>(xwB, xtB, cls_w_W, cls_w_b, cls_t_W, cls_t_b, d_out, mode);
}

// Round 5
// 1177.893 us; speedup vs baseline: 1.3344x; 1.1753x over previous
//
#include <hip/hip_runtime.h>
#include <stdint.h>

typedef unsigned short ushort_t;
typedef short s8v __attribute__((ext_vector_type(8)));
typedef float f4v __attribute__((ext_vector_type(4)));

#define NW 200000
#define NT 100000
#define EE 500000
#define NSEG (NT + NW + NW)   // concatenated dst slots: [tok(e_wt) | wal(e_tw) | wal(e_ww)]

__device__ __forceinline__ float b2f(unsigned short u){
  union { unsigned int i; float f; } v; v.i = ((unsigned int)u) << 16; return v.f;
}
__device__ __forceinline__ unsigned short f2b(float f){
  unsigned int x = __float_as_uint(f);
  unsigned int r = x + 0x7fffu + ((x >> 16) & 1u);   // RNE
  return (unsigned short)(r >> 16);
}
__device__ __forceinline__ float ldf(const void* p, long idx, int fm){
  return fm ? ((const float*)p)[idx] : b2f(((const ushort_t*)p)[idx]);
}

// ---------------- runtime dtype probes ----------------
// mode[0]: 1 = edges are int64, 0 = int32 ; mode[1]: 1 = floats are fp32, 0 = bf16
__global__ void detect_kern(const int* ewt, const int* etw, const int* eww,
                            const unsigned* xw_words, int* mode){
  if (threadIdx.x == 0 && blockIdx.x == 0){
    unsigned o = 0;
    for (int i = 0; i < 64; ++i)
      o |= (unsigned)ewt[2 * i + 1] | (unsigned)etw[2 * i + 1] | (unsigned)eww[2 * i + 1];
    mode[0] = (o == 0) ? 1 : 0;
    int viol = 0;
    for (int i = 0; i < 256; ++i){
      unsigned s = xw_words[i] & 0xffffu;
      unsigned e = (s >> 7) & 0xffu;
      if (!(s == 0u || s == 0x8000u || (e >= 90u && e <= 140u))) viol++;
    }
    mode[1] = (viol > 8) ? 1 : 0;
  }
}

// ------ batched weight transpose+convert: dst[n*K+k] = bf16(src[ebase + k*N + n]) ------
struct TDesc { const void* src; ushort_t* dst; long ebase; int K; int N; };
struct TDesc8 { TDesc d[8]; };
__global__ void transpose8(TDesc8 td, const int* mode){
  int fm = mode[1];
  int mi = blockIdx.x >> 6;
  TDesc t = td.d[mi];
  int e = ((blockIdx.x & 63) << 8) + threadIdx.x;
  if (e < t.K * t.N){
    int k = e / t.N, n = e - k * t.N;
    t.dst[n * t.K + k] = f2b(ldf(t.src, t.ebase + e, fm));
  }
}

// ---------------- fold att vectors into U matvec weights ----------------
// wallet cols j: 0,1=a_s type0 (h0,h1); 2,3=a_s type2; 4,5=a_d type1; 6,7=a_d type2
// token  cols jj: 0,1=a_s type1; 2,3=a_d type0
__global__ void uprep(const void* Wsrc0, const void* Wdst0, const void* atts0, const void* attd0,
                      const void* Wsrc1, const void* Wdst1, const void* atts1, const void* attd1,
                      float* Uw0, float* Ut0, float* Uw1, float* Ut1, const int* mode){
  int fm = mode[1];
  int id = blockIdx.x * 256 + threadIdx.x;
  if (id >= (64 + 128) * 12) return;
  int layer = (id >= 64 * 12);
  int rem = layer ? id - 64 * 12 : id;
  int K = layer ? 128 : 64;
  int k = rem / 12, j = rem % 12;
  const void* Ws = layer ? Wsrc1 : Wsrc0;
  const void* Wd = layer ? Wdst1 : Wdst0;
  const void* As = layer ? atts1 : atts0;
  const void* Ad = layer ? attd1 : attd0;
  int t, h; bool src;
  if (j < 8){ const int tt[8] = {0,0,2,2,1,1,2,2}; t = tt[j]; h = j & 1; src = (j < 4); }
  else { int jj = j - 8; t = (jj < 2) ? 1 : 0; h = jj & 1; src = (jj < 2); }
  const void* W = src ? Ws : Wd;
  const void* A = src ? As : Ad;
  float acc = 0.f;
  for (int c = 0; c < 64; ++c)
    acc += ldf(W, (long)(t * K + k) * 128 + h * 64 + c, fm) * ldf(A, t * 128 + h * 64 + c, fm);
  if (j < 8) (layer ? Uw1 : Uw0)[k * 8 + j] = acc;
  else       (layer ? Ut1 : Ut0)[k * 4 + (j - 8)] = acc;
}

// ---------------- CSR build ----------------
__global__ void hist_kern(const int* ewt, const int* etw, const int* eww, const int* mode, int* deg){
  int i = blockIdx.x * 256 + threadIdx.x;
  if (i >= 3 * EE) return;
  int md = mode[0];
  int t = i / EE, e = i - t * EE;
  const int* ep = (t == 0) ? ewt : (t == 1) ? etw : eww;
  int d = md ? ep[2 * (EE + e)] : ep[EE + e];
  int base = (t == 0) ? 0 : (t == 1) ? NT : NT + NW;
  atomicAdd(&deg[base + d], 1);
}

__global__ __launch_bounds__(512) void scan1(const int* deg, int* excl, int* sums){
  __shared__ int pair[512];
  int t = threadIdx.x;
  int base = blockIdx.x * 1024;
  int i0 = base + 2 * t;
  int a = (i0 < NSEG) ? deg[i0] : 0;
  int b = (i0 + 1 < NSEG) ? deg[i0 + 1] : 0;
  int ps = a + b;
  pair[t] = ps;
  __syncthreads();
  for (int off = 1; off < 512; off <<= 1){
    int v = (t >= off) ? pair[t - off] : 0;
    __syncthreads();
    if (t >= off) pair[t] += v;
    __syncthreads();
  }
  int epair = pair[t] - ps;
  if (i0 < NSEG) excl[i0] = epair;
  if (i0 + 1 < NSEG) excl[i0 + 1] = epair + a;
  if (t == 511) sums[blockIdx.x] = pair[511];
}

__global__ __launch_bounds__(512) void scan2(int* sums, int nch){
  __shared__ int s[512];
  int t = threadIdx.x;
  int orig = (t < nch) ? sums[t] : 0;
  s[t] = orig;
  __syncthreads();
  for (int off = 1; off < 512; off <<= 1){
    int v = (t >= off) ? s[t - off] : 0;
    __syncthreads();
    if (t >= off) s[t] += v;
    __syncthreads();
  }
  if (t < nch) sums[t] = s[t] - orig;
}

__global__ void scan3(int* rowptr, int* cursor, const int* sums){
  int i = blockIdx.x * 256 + threadIdx.x;
  if (i < NSEG){
    int v = rowptr[i] + sums[i >> 10];
    rowptr[i] = v; cursor[i] = v;
  }
  if (i == 0) rowptr[NSEG] = 3 * EE;
}

__global__ void fill_kern(const int* ewt, const int* etw, const int* eww, const int* mode,
                          int* cursor, int* adj, int* dstarr){
  int i = blockIdx.x * 256 + threadIdx.x;
  if (i >= 3 * EE) return;
  int md = mode[0];
  int t = i / EE, e = i - t * EE;
  const int* ep = (t == 0) ? ewt : (t == 1) ? etw : eww;
  int s = md ? ep[2 * e] : ep[e];
  int d = md ? ep[2 * (EE + e)] : ep[EE + e];
  int base = (t == 0) ? 0 : (t == 1) ? NT : NT + NW;
  int pos = atomicAdd(&cursor[base + d], 1);
  adj[pos] = s;
  dstarr[pos] = base + d;
}

// -------- B-stationary MFMA GEMM: C[M,NC] = A[M,K] @ Bt^T, Bt is [NC][K] bf16 --------
template<int K, int NC, bool BIAS, bool EXTA>
__global__ __launch_bounds__(256, 2) void gemm_kern(const void* __restrict__ A, const ushort_t* __restrict__ Bt,
    const void* __restrict__ bias, ushort_t* __restrict__ C, int M,
    const int* __restrict__ mode, int nchunk){
  constexpr int CT = NC / 16, KK = K / 32;
  int fm = EXTA ? mode[1] : 0;
  int tid = threadIdx.x, lane = tid & 63, wave = tid >> 6;
  int rl = lane & 15, kq = (lane >> 4) * 8;
  s8v bfrag[CT][KK];
#pragma unroll
  for (int ct = 0; ct < CT; ++ct)
#pragma unroll
    for (int kk = 0; kk < KK; ++kk)
      bfrag[ct][kk] = *(const s8v*)(Bt + (long)(ct * 16 + rl) * K + kk * 32 + kq);
  float biasv[CT];
  if (BIAS){
#pragma unroll
    for (int ct = 0; ct < CT; ++ct) biasv[ct] = ldf(bias, ct * 16 + rl, fm);
  }
  for (int chunk = blockIdx.x; chunk < nchunk; chunk += gridDim.x){
    long m0 = (long)chunk * 128 + wave * 32;
    f4v acc[2][CT];
#pragma unroll
    for (int rt = 0; rt < 2; ++rt)
#pragma unroll
      for (int ct = 0; ct < CT; ++ct) acc[rt][ct] = (f4v){0.f, 0.f, 0.f, 0.f};
#pragma unroll
    for (int rt = 0; rt < 2; ++rt){
      long row = m0 + rt * 16 + rl;
      bool ok = row < (long)M;
#pragma unroll
      for (int kk = 0; kk < KK; ++kk){
        s8v a = (s8v){0,0,0,0,0,0,0,0};
        if (ok){
          long e = row * K + kk * 32 + kq;
          if (EXTA && fm){
            const float* p = (const float*)A + e;
            uint4 lo = *(const uint4*)p;
            uint4 hi = *(const uint4*)(p + 4);
            union { s8v v; unsigned u[4]; } t;
            t.u[0] = (unsigned)f2b(__uint_as_float(lo.x)) | ((unsigned)f2b(__uint_as_float(lo.y)) << 16);
            t.u[1] = (unsigned)f2b(__uint_as_float(lo.z)) | ((unsigned)f2b(__uint_as_float(lo.w)) << 16);
            t.u[2] = (unsigned)f2b(__uint_as_float(hi.x)) | ((unsigned)f2b(__uint_as_float(hi.y)) << 16);
            t.u[3] = (unsigned)f2b(__uint_as_float(hi.z)) | ((unsigned)f2b(__uint_as_float(hi.w)) << 16);
            a = t.v;
          } else {
            a = *(const s8v*)((const ushort_t*)A + e);
          }
        }
#pragma unroll
        for (int ct = 0; ct < CT; ++ct)
          acc[rt][ct] = __builtin_amdgcn_mfma_f32_16x16x32_bf16(a, bfrag[ct][kk], acc[rt][ct], 0, 0, 0);
      }
    }
#pragma unroll
    for (int rt = 0; rt < 2; ++rt){
      long rbase = (long)chunk * 128 + wave * 32 + rt * 16 + (lane >> 4) * 4;
#pragma unroll
      for (int ct = 0; ct < CT; ++ct){
#pragma unroll
        for (int r = 0; r < 4; ++r){
          long gm = rbase + r;
          if (gm < (long)M){
            float v = acc[rt][ct][r];
            if (BIAS) v += biasv[ct];
            C[gm * NC + ct * 16 + rl] = f2b(v);
          }
        }
      }
    }
  }
}

// ------- per-node attention scalars, thread-per-node: out[N,NCOL] = x[N,K] @ U -------
// U accesses are wave-uniform -> scalar loads; fully unrolled FMA body, no shuffles.
template<int K, int NCOL>
__global__ __launch_bounds__(256) void a_kern(const ushort_t* __restrict__ x, const float* __restrict__ U,
                                              float* __restrict__ out, int N){
  int n = blockIdx.x * 256 + threadIdx.x;
  if (n >= N) return;
  float acc[NCOL];
#pragma unroll
  for (int j = 0; j < NCOL; ++j) acc[j] = 0.f;
  const ushort_t* xr = x + (long)n * K;
#pragma unroll
  for (int k8 = 0; k8 < K / 8; ++k8){
    uint4 v = *(const uint4*)(xr + k8 * 8);
    unsigned uu[4] = {v.x, v.y, v.z, v.w};
#pragma unroll
    for (int i = 0; i < 4; ++i){
      float f0 = b2f((unsigned short)(uu[i] & 0xffffu));
      float f1 = b2f((unsigned short)(uu[i] >> 16));
      const float* Ur = U + (k8 * 8 + i * 2) * NCOL;
#pragma unroll
      for (int j = 0; j < NCOL; ++j) acc[j] += f0 * Ur[j] + f1 * Ur[NCOL + j];
    }
  }
  f4v* o4 = (f4v*)(out + (long)n * NCOL);
#pragma unroll
  for (int q = 0; q < NCOL / 4; ++q){
    f4v t = {acc[q * 4], acc[q * 4 + 1], acc[q * 4 + 2], acc[q * 4 + 3]};
    o4[q] = t;
  }
}

// ---------------- phase A: per-edge-slot attention logits (both heads) ----------------
__global__ void edge_alpha(const int* __restrict__ adj, const int* __restrict__ dstarr,
                           const float* __restrict__ aw, const float* __restrict__ at,
                           float2* __restrict__ alf){
  int j = blockIdx.x * 256 + threadIdx.x;
  if (j >= 3 * EE) return;
  int s = adj[j], seg = dstarr[j];
  float2 as, ad;
  if (seg < NT){            // type0: wallet -> token
    as = *(const float2*)(aw + (long)s * 8 + 0);
    ad = *(const float2*)(at + (long)seg * 4 + 2);
  } else if (seg < NT + NW){ // type1: token -> wallet
    as = *(const float2*)(at + (long)s * 4 + 0);
    ad = *(const float2*)(aw + (long)(seg - NT) * 8 + 4);
  } else {                  // type2: wallet -> wallet
    as = *(const float2*)(aw + (long)s * 8 + 2);
    ad = *(const float2*)(aw + (long)(seg - NT - NW) * 8 + 6);
  }
  float a0 = as.x + ad.x, a1 = as.y + ad.y;
  a0 = a0 > 0.f ? a0 : 0.2f * a0;
  a1 = a1 > 0.f ? a1 : 0.2f * a1;
  alf[j] = make_float2(a0, a1);
}

// ---------------- phase B: per-segment softmax, thread-per-node ----------------
__global__ void seg_softmax(const int* __restrict__ rowptr, float2* __restrict__ alf){
  int seg = blockIdx.x * 256 + threadIdx.x;
  if (seg >= NSEG) return;
  int beg = rowptr[seg], end = rowptr[seg + 1];
  if (beg >= end) return;
  float m0 = -1e30f, m1 = -1e30f;
  for (int j = beg; j < end; ++j){
    float2 a = alf[j];
    m0 = fmaxf(m0, a.x); m1 = fmaxf(m1, a.y);
  }
  float d0 = 0.f, d1 = 0.f;
  for (int j = beg; j < end; ++j){
    float2 a = alf[j];
    a.x = __expf(a.x - m0); a.y = __expf(a.y - m1);
    d0 += a.x; d1 += a.y;
    alf[j] = a;
  }
  float i0 = 1.f / (d0 + 1e-16f), i1 = 1.f / (d1 + 1e-16f);
  for (int j = beg; j < end; ++j){
    float2 a = alf[j];
    alf[j] = make_float2(a.x * i0, a.y * i1);
  }
}

// ---------------- phase C: pure weighted gather (wave per dst node) ----------------
__device__ __forceinline__ void conv_gather(const int* __restrict__ rowptr, const int* __restrict__ adj,
    const float2* __restrict__ alf, int seg, const ushort_t* __restrict__ hs,
    int lane, int c0, float& o0, float& o1){
  int beg = rowptr[seg], end = rowptr[seg + 1];
  for (int j = beg; j < end; ++j){
    float2 w2 = alf[j];                 // broadcast (8B, all lanes same addr)
    int s = adj[j];                     // broadcast
    float w = (lane < 32) ? w2.x : w2.y;
    unsigned hv = *(const unsigned*)(hs + (long)s * 128 + c0);   // coalesced 256B/wave
    o0 += w * b2f((unsigned short)(hv & 0xffffu));
    o1 += w * b2f((unsigned short)(hv >> 16));
  }
}

__global__ __launch_bounds__(256) void wallet_agg(const int* __restrict__ rowptr, const int* __restrict__ adj,
    const float2* __restrict__ alf, const ushort_t* __restrict__ hs1, const ushort_t* __restrict__ hs2,
    const void* __restrict__ bsrc, ushort_t* __restrict__ out, const int* __restrict__ mode){
  int fm = mode[1];
  int d = blockIdx.x * 4 + (threadIdx.x >> 6);
  if (d >= NW) return;
  int lane = threadIdx.x & 63;
  int c0 = lane << 1;
  float o0 = 0.f, o1 = 0.f;
  conv_gather(rowptr, adj, alf, NT + d,      hs1, lane, c0, o0, o1);
  conv_gather(rowptr, adj, alf, NT + NW + d, hs2, lane, c0, o0, o1);
  o0 += ldf(bsrc, 128 + c0, fm)     + ldf(bsrc, 256 + c0, fm);      // b[1] + b[2] rows
  o1 += ldf(bsrc, 128 + c0 + 1, fm) + ldf(bsrc, 256 + c0 + 1, fm);
  o0 = o0 > 0.f ? o0 : expm1f(o0);
  o1 = o1 > 0.f ? o1 : expm1f(o1);
  unsigned pack = (unsigned)f2b(o0) | ((unsigned)f2b(o1) << 16);
  *(unsigned*)(out + (long)d * 128 + c0) = pack;
}

__global__ __launch_bounds__(256) void token_agg(const int* __restrict__ rowptr, const int* __restrict__ adj,
    const float2* __restrict__ alf, const ushort_t* __restrict__ hs0,
    const void* __restrict__ bsrc, ushort_t* __restrict__ out, const int* __restrict__ mode){
  int fm = mode[1];
  int d = blockIdx.x * 4 + (threadIdx.x >> 6);
  if (d >= NT) return;
  int lane = threadIdx.x & 63;
  int c0 = lane << 1;
  float o0 = 0.f, o1 = 0.f;
  conv_gather(rowptr, adj, alf, d, hs0, lane, c0, o0, o1);
  o0 += ldf(bsrc, c0, fm);          // b[0] row
  o1 += ldf(bsrc, c0 + 1, fm);
  o0 = o0 > 0.f ? o0 : expm1f(o0);
  o1 = o1 > 0.f ? o1 : expm1f(o1);
  unsigned pack = (unsigned)f2b(o0) | ((unsigned)f2b(o1) << 16);
  *(unsigned*)(out + (long)d * 128 + c0) = pack;
}

// ---------------- classifier (dtype-aware weights + output) ----------------
__global__ __launch_bounds__(256) void cls_kern(const ushort_t* __restrict__ xw, const ushort_t* __restrict__ xt,
    const void* __restrict__ Ww, const void* __restrict__ bw,
    const void* __restrict__ Wt, const void* __restrict__ bt, void* __restrict__ out,
    const int* __restrict__ mode){
  int fm = mode[1];
  int g = blockIdx.x * 4 + (threadIdx.x >> 6);
  if (g >= NW + NT) return;
  int lane = threadIdx.x & 63;
  const ushort_t* x; const void* W; const void* b;
  if (g < NW){ x = xw + (long)g * 128; W = Ww; b = bw; }
  else { x = xt + (long)(g - NW) * 128; W = Wt; b = bt; }
  unsigned xv = *(const unsigned*)(x + 2 * lane);
  float x0 = b2f((unsigned short)(xv & 0xffffu)), x1 = b2f((unsigned short)(xv >> 16));
  float w00 = ldf(W, 4 * lane + 0, fm), w01 = ldf(W, 4 * lane + 1, fm);
  float w10 = ldf(W, 4 * lane + 2, fm), w11 = ldf(W, 4 * lane + 3, fm);
  float p0 = x0 * w00 + x1 * w10;
  float p1 = x0 * w01 + x1 * w11;
#pragma unroll
  for (int off = 32; off > 0; off >>= 1){ p0 += __shfl_xor(p0, off, 64); p1 += __shfl_xor(p1, off, 64); }
  if (lane == 0){
    float r0 = p0 + ldf(b, 0, fm);
    float r1 = p1 + ldf(b, 1, fm);
    if (fm){
      ((float*)out)[(long)g * 2]     = r0;
      ((float*)out)[(long)g * 2 + 1] = r1;
    } else {
      ((ushort_t*)out)[(long)g * 2]     = f2b(r0);
      ((ushort_t*)out)[(long)g * 2 + 1] = f2b(r1);
    }
  }
}

extern "C" void kernel_launch(void* const* d_in, const int* in_sizes, int n_in,
                              void* d_out, int out_size, void* d_ws, size_t ws_size,
                              hipStream_t stream){
  const void* x_wallet = d_in[0];
  const void* x_token  = d_in[1];
  const void* lin_w_W  = d_in[2];
  const void* lin_w_b  = d_in[3];
  const void* lin_t_W  = d_in[4];
  const void* lin_t_b  = d_in[5];
  const void* Wsrc0    = d_in[6];
  const void* Wdst0    = d_in[7];
  const void* atts0    = d_in[8];
  const void* attd0    = d_in[9];
  const void* b0       = d_in[10];
  const void* Wsrc1    = d_in[11];
  const void* Wdst1    = d_in[12];
  const void* atts1    = d_in[13];
  const void* attd1    = d_in[14];
  const void* b1       = d_in[15];
  const void* cls_w_W  = d_in[16];
  const void* cls_w_b  = d_in[17];
  const void* cls_t_W  = d_in[18];
  const void* cls_t_b  = d_in[19];
  const int* e_wt = (const int*)d_in[20];
  const int* e_tw = (const int*)d_in[21];
  const int* e_ww = (const int*)d_in[22];

  char* ws = (char*)d_ws;
  size_t off = 0;
  auto alloc = [&](size_t bytes) -> char* {
    char* p = ws + off; off += (bytes + 255) & ~(size_t)255; return p;
  };
  int* rowptr = (int*)alloc((size_t)(NSEG + 1) * 4);
  int* deg    = (int*)alloc((size_t)(NSEG + 1) * 4);   // doubles as fill cursor after scan
  int* adj    = (int*)alloc((size_t)3 * EE * 4);
  int* dstarr = (int*)alloc((size_t)3 * EE * 4);
  float2* alf = (float2*)alloc((size_t)3 * EE * 8);
  int* sums   = (int*)alloc(512 * 4);
  int* mode   = (int*)alloc(8);
  ushort_t* BtLw = (ushort_t*)alloc(64 * 128 * 2);
  ushort_t* BtLt = (ushort_t*)alloc(64 * 64 * 2);
  ushort_t* BtS0 = (ushort_t*)alloc(3 * 128 * 64 * 2);
  ushort_t* BtS1 = (ushort_t*)alloc(3 * 128 * 128 * 2);
  float* Uw0 = (float*)alloc(64 * 8 * 4);
  float* Ut0 = (float*)alloc(64 * 4 * 4);
  float* Uw1 = (float*)alloc(128 * 8 * 4);
  float* Ut1 = (float*)alloc(128 * 4 * 4);
  float* aw = (float*)alloc((size_t)NW * 8 * 4);
  float* at = (float*)alloc((size_t)NT * 4 * 4);
  ushort_t* hs0 = (ushort_t*)alloc((size_t)NW * 128 * 2);
  ushort_t* hs1 = (ushort_t*)alloc((size_t)NT * 128 * 2);
  ushort_t* hs2 = (ushort_t*)alloc((size_t)NW * 128 * 2);
  ushort_t* xbuf = (ushort_t*)alloc(((size_t)NW + NT) * 128 * 2);
  ushort_t* xw0 = xbuf;
  ushort_t* xt0 = xbuf + (size_t)NW * 64;
  ushort_t* xwB = xbuf;                         // aliases xw0+xt0 (both dead by then)
  ushort_t* xtB = xbuf + (size_t)NW * 128;      // disjoint from xw0/xt0
  (void)in_sizes; (void)n_in;

  if (off > ws_size){
    hipMemsetAsync(d_out, 0, (size_t)out_size * 2, stream);
    return;
  }

  hipMemsetAsync(deg, 0, (size_t)NSEG * 4, stream);
  detect_kern<<<1, 64, 0, stream>>>(e_wt, e_tw, e_ww, (const unsigned*)x_wallet, mode);

  TDesc8 td;
  td.d[0] = { lin_w_W, BtLw, 0, 128, 64 };
  td.d[1] = { lin_t_W, BtLt, 0, 64, 64 };
  for (int t = 0; t < 3; ++t){
    td.d[2 + t] = { Wsrc0, BtS0 + t * 128 * 64,  (long)t * 64 * 128,  64,  128 };
    td.d[5 + t] = { Wsrc1, BtS1 + t * 128 * 128, (long)t * 128 * 128, 128, 128 };
  }
  transpose8<<<512, 256, 0, stream>>>(td, mode);
  uprep<<<9, 256, 0, stream>>>(Wsrc0, Wdst0, atts0, attd0, Wsrc1, Wdst1, atts1, attd1, Uw0, Ut0, Uw1, Ut1, mode);

  int egrid = (3 * EE + 255) / 256;
  hist_kern<<<egrid, 256, 0, stream>>>(e_wt, e_tw, e_ww, mode, deg);
  int nch = (NSEG + 1023) / 1024;
  scan1<<<nch, 512, 0, stream>>>(deg, rowptr, sums);
  scan2<<<1, 512, 0, stream>>>(sums, nch);
  scan3<<<(NSEG + 255) / 256, 256, 0, stream>>>(rowptr, deg, sums);   // deg becomes cursor
  fill_kern<<<egrid, 256, 0, stream>>>(e_wt, e_tw, e_ww, mode, deg, adj, dstarr);

  const int G = 512;
  int ncW = (NW + 127) / 128, ncT = (NT + 127) / 128;
  int sgrid = (NSEG + 255) / 256;

  // input projections (external A, dtype per mode[1])
  gemm_kern<128, 64, true, true><<<G, 256, 0, stream>>>(x_wallet, BtLw, lin_w_b, xw0, NW, mode, ncW);
  gemm_kern<64, 64, true, true><<<G, 256, 0, stream>>>(x_token, BtLt, lin_t_b, xt0, NT, mode, ncT);

  // ---- layer 0 (K=64) ----
  a_kern<64, 8><<<(NW + 255) / 256, 256, 0, stream>>>(xw0, Uw0, aw, NW);
  a_kern<64, 4><<<(NT + 255) / 256, 256, 0, stream>>>(xt0, Ut0, at, NT);
  gemm_kern<64, 128, false, false><<<G, 256, 0, stream>>>(xw0, BtS0, nullptr, hs0, NW, mode, ncW);
  gemm_kern<64, 128, false, false><<<G, 256, 0, stream>>>(xt0, BtS0 + 128 * 64, nullptr, hs1, NT, mode, ncT);
  gemm_kern<64, 128, false, false><<<G, 256, 0, stream>>>(xw0, BtS0 + 2 * 128 * 64, nullptr, hs2, NW, mode, ncW);
  edge_alpha<<<egrid, 256, 0, stream>>>(adj, dstarr, aw, at, alf);
  seg_softmax<<<sgrid, 256, 0, stream>>>(rowptr, alf);
  token_agg<<<NT / 4, 256, 0, stream>>>(rowptr, adj, alf, hs0, b0, xtB, mode);
  wallet_agg<<<NW / 4, 256, 0, stream>>>(rowptr, adj, alf, hs1, hs2, b0, xwB, mode);

  // ---- layer 1 (K=128) ----
  a_kern<128, 8><<<(NW + 255) / 256, 256, 0, stream>>>(xwB, Uw1, aw, NW);
  a_kern<128, 4><<<(NT + 255) / 256, 256, 0, stream>>>(xtB, Ut1, at, NT);
  gemm_kern<128, 128, false, false><<<G, 256, 0, stream>>>(xwB, BtS1, nullptr, hs0, NW, mode, ncW);
  gemm_kern<128, 128, false, false><<<G, 256, 0, stream>>>(xtB, BtS1 + 128 * 128, nullptr, hs1, NT, mode, ncT);
  gemm_kern<128, 128, false, false><<<G, 256, 0, stream>>>(xwB, BtS1 + 2 * 128 * 128, nullptr, hs2, NW, mode, ncW);
  edge_alpha<<<egrid, 256, 0, stream>>>(adj, dstarr, aw, at, alf);
  seg_softmax<<<sgrid, 256, 0, stream>>>(rowptr, alf);
  wallet_agg<<<NW / 4, 256, 0, stream>>>(rowptr, adj, alf, hs1, hs2, b1, xwB, mode);
  token_agg<<<NT / 4, 256, 0, stream>>>(rowptr, adj, alf, hs0, b1, xtB, mode);

  // classifier (dtype-aware output)
  cls_kern<<<(NW + NT) / 4, 256, 0, stream>>>(xwB, xtB, cls_w_W, cls_w_b, cls_t_W, cls_t_b, d_out, mode);
}

// Round 6
// 1121.131 us; speedup vs baseline: 1.4020x; 1.0506x over previous
//
#include <hip/hip_runtime.h>
#include <stdint.h>

typedef unsigned short ushort_t;
typedef short s8v __attribute__((ext_vector_type(8)));
typedef float f4v __attribute__((ext_vector_type(4)));

#define NW 200000
#define NT 100000
#define EE 500000
#define NSEG (NT + NW + NW)   // concatenated dst slots: [tok(e_wt) | wal(e_tw) | wal(e_ww)]

__device__ __forceinline__ float b2f(unsigned short u){
  union { unsigned int i; float f; } v; v.i = ((unsigned int)u) << 16; return v.f;
}
__device__ __forceinline__ unsigned short f2b(float f){
  unsigned int x = __float_as_uint(f);
  unsigned int r = x + 0x7fffu + ((x >> 16) & 1u);   // RNE
  return (unsigned short)(r >> 16);
}
__device__ __forceinline__ float ldf(const void* p, long idx, int fm){
  return fm ? ((const float*)p)[idx] : b2f(((const ushort_t*)p)[idx]);
}

// ---------------- runtime dtype probes ----------------
// mode[0]: 1 = edges are int64, 0 = int32 ; mode[1]: 1 = floats are fp32, 0 = bf16
__global__ void detect_kern(const int* ewt, const int* etw, const int* eww,
                            const unsigned* xw_words, int* mode){
  if (threadIdx.x == 0 && blockIdx.x == 0){
    unsigned o = 0;
    for (int i = 0; i < 64; ++i)
      o |= (unsigned)ewt[2 * i + 1] | (unsigned)etw[2 * i + 1] | (unsigned)eww[2 * i + 1];
    mode[0] = (o == 0) ? 1 : 0;
    int viol = 0;
    for (int i = 0; i < 256; ++i){
      unsigned s = xw_words[i] & 0xffffu;
      unsigned e = (s >> 7) & 0xffu;
      if (!(s == 0u || s == 0x8000u || (e >= 90u && e <= 140u))) viol++;
    }
    mode[1] = (viol > 8) ? 1 : 0;
  }
}

// ------ batched weight transpose+convert: dst[n*K+k] = bf16(src[ebase + k*N + n]) ------
struct TDesc { const void* src; ushort_t* dst; long ebase; int K; int N; };
struct TDesc8 { TDesc d[8]; };
__global__ void transpose8(TDesc8 td, const int* mode){
  int fm = mode[1];
  int mi = blockIdx.x >> 6;
  TDesc t = td.d[mi];
  int e = ((blockIdx.x & 63) << 8) + threadIdx.x;
  if (e < t.K * t.N){
    int k = e / t.N, n = e - k * t.N;
    t.dst[n * t.K + k] = f2b(ldf(t.src, t.ebase + e, fm));
  }
}

// ---------------- fold att vectors into U matvec weights ----------------
// wallet cols j: 0,1=a_s type0 (h0,h1); 2,3=a_s type2; 4,5=a_d type1; 6,7=a_d type2
// token  cols jj: 0,1=a_s type1; 2,3=a_d type0
__global__ void uprep(const void* Wsrc0, const void* Wdst0, const void* atts0, const void* attd0,
                      const void* Wsrc1, const void* Wdst1, const void* atts1, const void* attd1,
                      float* Uw0, float* Ut0, float* Uw1, float* Ut1, const int* mode){
  int fm = mode[1];
  int id = blockIdx.x * 256 + threadIdx.x;
  if (id >= (64 + 128) * 12) return;
  int layer = (id >= 64 * 12);
  int rem = layer ? id - 64 * 12 : id;
  int K = layer ? 128 : 64;
  int k = rem / 12, j = rem % 12;
  const void* Ws = layer ? Wsrc1 : Wsrc0;
  const void* Wd = layer ? Wdst1 : Wdst0;
  const void* As = layer ? atts1 : atts0;
  const void* Ad = layer ? attd1 : attd0;
  int t, h; bool src;
  if (j < 8){ const int tt[8] = {0,0,2,2,1,1,2,2}; t = tt[j]; h = j & 1; src = (j < 4); }
  else { int jj = j - 8; t = (jj < 2) ? 1 : 0; h = jj & 1; src = (jj < 2); }
  const void* W = src ? Ws : Wd;
  const void* A = src ? As : Ad;
  float acc = 0.f;
  for (int c = 0; c < 64; ++c)
    acc += ldf(W, (long)(t * K + k) * 128 + h * 64 + c, fm) * ldf(A, t * 128 + h * 64 + c, fm);
  if (j < 8) (layer ? Uw1 : Uw0)[k * 8 + j] = acc;
  else       (layer ? Ut1 : Ut0)[k * 4 + (j - 8)] = acc;
}

// ---------------- CSR build ----------------
__global__ void hist_kern(const int* ewt, const int* etw, const int* eww, const int* mode, int* deg){
  int i = blockIdx.x * 256 + threadIdx.x;
  if (i >= 3 * EE) return;
  int md = mode[0];
  int t = i / EE, e = i - t * EE;
  const int* ep = (t == 0) ? ewt : (t == 1) ? etw : eww;
  int d = md ? ep[2 * (EE + e)] : ep[EE + e];
  int base = (t == 0) ? 0 : (t == 1) ? NT : NT + NW;
  atomicAdd(&deg[base + d], 1);
}

__global__ __launch_bounds__(512) void scan1(const int* deg, int* excl, int* sums){
  __shared__ int pair[512];
  int t = threadIdx.x;
  int base = blockIdx.x * 1024;
  int i0 = base + 2 * t;
  int a = (i0 < NSEG) ? deg[i0] : 0;
  int b = (i0 + 1 < NSEG) ? deg[i0 + 1] : 0;
  int ps = a + b;
  pair[t] = ps;
  __syncthreads();
  for (int off = 1; off < 512; off <<= 1){
    int v = (t >= off) ? pair[t - off] : 0;
    __syncthreads();
    if (t >= off) pair[t] += v;
    __syncthreads();
  }
  int epair = pair[t] - ps;
  if (i0 < NSEG) excl[i0] = epair;
  if (i0 + 1 < NSEG) excl[i0 + 1] = epair + a;
  if (t == 511) sums[blockIdx.x] = pair[511];
}

__global__ __launch_bounds__(512) void scan2(int* sums, int nch){
  __shared__ int s[512];
  int t = threadIdx.x;
  int orig = (t < nch) ? sums[t] : 0;
  s[t] = orig;
  __syncthreads();
  for (int off = 1; off < 512; off <<= 1){
    int v = (t >= off) ? s[t - off] : 0;
    __syncthreads();
    if (t >= off) s[t] += v;
    __syncthreads();
  }
  if (t < nch) sums[t] = s[t] - orig;
}

__global__ void scan3(int* rowptr, int* cursor, const int* sums){
  int i = blockIdx.x * 256 + threadIdx.x;
  if (i < NSEG){
    int v = rowptr[i] + sums[i >> 10];
    rowptr[i] = v; cursor[i] = v;
  }
  if (i == 0) rowptr[NSEG] = 3 * EE;
}

__global__ void fill_kern(const int* ewt, const int* etw, const int* eww, const int* mode,
                          int* cursor, int* adj){
  int i = blockIdx.x * 256 + threadIdx.x;
  if (i >= 3 * EE) return;
  int md = mode[0];
  int t = i / EE, e = i - t * EE;
  const int* ep = (t == 0) ? ewt : (t == 1) ? etw : eww;
  int s = md ? ep[2 * e] : ep[e];
  int d = md ? ep[2 * (EE + e)] : ep[EE + e];
  int base = (t == 0) ? 0 : (t == 1) ? NT : NT + NW;
  int pos = atomicAdd(&cursor[base + d], 1);
  adj[pos] = s;
}

// -------- B-stationary MFMA GEMM: C[M,NC] = A[M,K] @ Bt^T, Bt is [NC][K] bf16 --------
template<int K, int NC, bool BIAS, bool EXTA>
__global__ __launch_bounds__(256, 2) void gemm_kern(const void* __restrict__ A, const ushort_t* __restrict__ Bt,
    const void* __restrict__ bias, ushort_t* __restrict__ C, int M,
    const int* __restrict__ mode, int nchunk){
  constexpr int CT = NC / 16, KK = K / 32;
  int fm = EXTA ? mode[1] : 0;
  int tid = threadIdx.x, lane = tid & 63, wave = tid >> 6;
  int rl = lane & 15, kq = (lane >> 4) * 8;
  s8v bfrag[CT][KK];
#pragma unroll
  for (int ct = 0; ct < CT; ++ct)
#pragma unroll
    for (int kk = 0; kk < KK; ++kk)
      bfrag[ct][kk] = *(const s8v*)(Bt + (long)(ct * 16 + rl) * K + kk * 32 + kq);
  float biasv[CT];
  if (BIAS){
#pragma unroll
    for (int ct = 0; ct < CT; ++ct) biasv[ct] = ldf(bias, ct * 16 + rl, fm);
  }
  for (int chunk = blockIdx.x; chunk < nchunk; chunk += gridDim.x){
    long m0 = (long)chunk * 128 + wave * 32;
    f4v acc[2][CT];
#pragma unroll
    for (int rt = 0; rt < 2; ++rt)
#pragma unroll
      for (int ct = 0; ct < CT; ++ct) acc[rt][ct] = (f4v){0.f, 0.f, 0.f, 0.f};
#pragma unroll
    for (int rt = 0; rt < 2; ++rt){
      long row = m0 + rt * 16 + rl;
      bool ok = row < (long)M;
#pragma unroll
      for (int kk = 0; kk < KK; ++kk){
        s8v a = (s8v){0,0,0,0,0,0,0,0};
        if (ok){
          long e = row * K + kk * 32 + kq;
          if (EXTA && fm){
            const float* p = (const float*)A + e;
            uint4 lo = *(const uint4*)p;
            uint4 hi = *(const uint4*)(p + 4);
            union { s8v v; unsigned u[4]; } t;
            t.u[0] = (unsigned)f2b(__uint_as_float(lo.x)) | ((unsigned)f2b(__uint_as_float(lo.y)) << 16);
            t.u[1] = (unsigned)f2b(__uint_as_float(lo.z)) | ((unsigned)f2b(__uint_as_float(lo.w)) << 16);
            t.u[2] = (unsigned)f2b(__uint_as_float(hi.x)) | ((unsigned)f2b(__uint_as_float(hi.y)) << 16);
            t.u[3] = (unsigned)f2b(__uint_as_float(hi.z)) | ((unsigned)f2b(__uint_as_float(hi.w)) << 16);
            a = t.v;
          } else {
            a = *(const s8v*)((const ushort_t*)A + e);
          }
        }
#pragma unroll
        for (int ct = 0; ct < CT; ++ct)
          acc[rt][ct] = __builtin_amdgcn_mfma_f32_16x16x32_bf16(a, bfrag[ct][kk], acc[rt][ct], 0, 0, 0);
      }
    }
#pragma unroll
    for (int rt = 0; rt < 2; ++rt){
      long rbase = (long)chunk * 128 + wave * 32 + rt * 16 + (lane >> 4) * 4;
#pragma unroll
      for (int ct = 0; ct < CT; ++ct){
#pragma unroll
        for (int r = 0; r < 4; ++r){
          long gm = rbase + r;
          if (gm < (long)M){
            float v = acc[rt][ct][r];
            if (BIAS) v += biasv[ct];
            C[gm * NC + ct * 16 + rl] = f2b(v);
          }
        }
      }
    }
  }
}

// ------- per-node attention scalars, thread-per-node: out[N,NCOL] = x[N,K] @ U -------
template<int K, int NCOL>
__global__ __launch_bounds__(256) void a_kern(const ushort_t* __restrict__ x, const float* __restrict__ U,
                                              float* __restrict__ out, int N){
  int n = blockIdx.x * 256 + threadIdx.x;
  if (n >= N) return;
  float acc[NCOL];
#pragma unroll
  for (int j = 0; j < NCOL; ++j) acc[j] = 0.f;
  const ushort_t* xr = x + (long)n * K;
#pragma unroll
  for (int k8 = 0; k8 < K / 8; ++k8){
    uint4 v = *(const uint4*)(xr + k8 * 8);
    unsigned uu[4] = {v.x, v.y, v.z, v.w};
#pragma unroll
    for (int i = 0; i < 4; ++i){
      float f0 = b2f((unsigned short)(uu[i] & 0xffffu));
      float f1 = b2f((unsigned short)(uu[i] >> 16));
      const float* Ur = U + (k8 * 8 + i * 2) * NCOL;
#pragma unroll
      for (int j = 0; j < NCOL; ++j) acc[j] += f0 * Ur[j] + f1 * Ur[NCOL + j];
    }
  }
  f4v* o4 = (f4v*)(out + (long)n * NCOL);
#pragma unroll
  for (int q = 0; q < NCOL / 4; ++q){
    f4v t = {acc[q * 4], acc[q * 4 + 1], acc[q * 4 + 2], acc[q * 4 + 3]};
    o4[q] = t;
  }
}

// ------- fused per-node softmax (thread per dst slot), batch-4 pipelined -------
// Writes UNNORMALIZED exp weights into alf and 1/den into inv[seg] (both heads).
// Clamped-index trick: duplicate computations are idempotent; den masks validity.
__global__ __launch_bounds__(256) void node_softmax(const int* __restrict__ rowptr,
    const int* __restrict__ adj, const float* __restrict__ aw, const float* __restrict__ at,
    float2* __restrict__ alf, float2* __restrict__ inv){
  int seg = blockIdx.x * 256 + threadIdx.x;
  if (seg >= NSEG) return;
  int beg = rowptr[seg], end = rowptr[seg + 1];
  if (beg >= end){ inv[seg] = make_float2(0.f, 0.f); return; }
  const float* asrc; int stride, col; float2 ad;
  if (seg < NT){            // type0: wallet -> token
    asrc = aw; stride = 8; col = 0;
    ad = *(const float2*)(at + (long)seg * 4 + 2);
  } else if (seg < NT + NW){ // type1: token -> wallet
    asrc = at; stride = 4; col = 0;
    ad = *(const float2*)(aw + (long)(seg - NT) * 8 + 4);
  } else {                  // type2: wallet -> wallet
    asrc = aw; stride = 8; col = 2;
    ad = *(const float2*)(aw + (long)(seg - NT - NW) * 8 + 6);
  }
  float m0 = -1e30f, m1 = -1e30f;
  for (int j = beg; j < end; j += 4){
    int j1 = min(j + 1, end - 1), j2 = min(j + 2, end - 1), j3 = min(j + 3, end - 1);
    int s0 = adj[j], s1 = adj[j1], s2 = adj[j2], s3 = adj[j3];
    float2 x0 = *(const float2*)(asrc + (long)s0 * stride + col);
    float2 x1 = *(const float2*)(asrc + (long)s1 * stride + col);
    float2 x2 = *(const float2*)(asrc + (long)s2 * stride + col);
    float2 x3 = *(const float2*)(asrc + (long)s3 * stride + col);
    float2 a0, a1, a2, a3;
    a0.x = x0.x + ad.x; a0.y = x0.y + ad.y;
    a1.x = x1.x + ad.x; a1.y = x1.y + ad.y;
    a2.x = x2.x + ad.x; a2.y = x2.y + ad.y;
    a3.x = x3.x + ad.x; a3.y = x3.y + ad.y;
    a0.x = a0.x > 0.f ? a0.x : 0.2f * a0.x;  a0.y = a0.y > 0.f ? a0.y : 0.2f * a0.y;
    a1.x = a1.x > 0.f ? a1.x : 0.2f * a1.x;  a1.y = a1.y > 0.f ? a1.y : 0.2f * a1.y;
    a2.x = a2.x > 0.f ? a2.x : 0.2f * a2.x;  a2.y = a2.y > 0.f ? a2.y : 0.2f * a2.y;
    a3.x = a3.x > 0.f ? a3.x : 0.2f * a3.x;  a3.y = a3.y > 0.f ? a3.y : 0.2f * a3.y;
    alf[j] = a0; alf[j1] = a1; alf[j2] = a2; alf[j3] = a3;   // idempotent duplicates
    m0 = fmaxf(fmaxf(m0, fmaxf(a0.x, a1.x)), fmaxf(a2.x, a3.x));
    m1 = fmaxf(fmaxf(m1, fmaxf(a0.y, a1.y)), fmaxf(a2.y, a3.y));
  }
  float d0 = 0.f, d1 = 0.f;
  for (int j = beg; j < end; j += 4){
    int j1 = min(j + 1, end - 1), j2 = min(j + 2, end - 1), j3 = min(j + 3, end - 1);
    float2 a0 = alf[j], a1 = alf[j1], a2 = alf[j2], a3 = alf[j3];
    a0.x = __expf(a0.x - m0); a0.y = __expf(a0.y - m1);
    a1.x = __expf(a1.x - m0); a1.y = __expf(a1.y - m1);
    a2.x = __expf(a2.x - m0); a2.y = __expf(a2.y - m1);
    a3.x = __expf(a3.x - m0); a3.y = __expf(a3.y - m1);
    alf[j] = a0; alf[j1] = a1; alf[j2] = a2; alf[j3] = a3;
    bool v1 = j + 1 < end, v2 = j + 2 < end, v3 = j + 3 < end;
    d0 += a0.x + (v1 ? a1.x : 0.f) + (v2 ? a2.x : 0.f) + (v3 ? a3.x : 0.f);
    d1 += a0.y + (v1 ? a1.y : 0.f) + (v2 ? a2.y : 0.f) + (v3 ? a3.y : 0.f);
  }
  inv[seg] = make_float2(1.f / (d0 + 1e-16f), 1.f / (d1 + 1e-16f));
}

// ---------------- weighted gather (wave per dst node), batch-4 pipelined ----------------
__device__ __forceinline__ void conv_gather(const int* __restrict__ rowptr, const int* __restrict__ adj,
    const float2* __restrict__ alf, const float2* __restrict__ inv, int seg,
    const ushort_t* __restrict__ hs, int lane, int c0, float& o0, float& o1){
  int beg = rowptr[seg], end = rowptr[seg + 1];
  if (beg >= end) return;
  float a0 = 0.f, a1 = 0.f;
  for (int j = beg; j < end; j += 4){
    int j1 = min(j + 1, end - 1), j2 = min(j + 2, end - 1), j3 = min(j + 3, end - 1);
    int s0 = adj[j], s1 = adj[j1], s2 = adj[j2], s3 = adj[j3];
    float2 w0 = alf[j], w1 = alf[j1], w2 = alf[j2], w3 = alf[j3];
    unsigned h0 = *(const unsigned*)(hs + (long)s0 * 128 + c0);   // 4 independent 256B/wave loads
    unsigned h1 = *(const unsigned*)(hs + (long)s1 * 128 + c0);
    unsigned h2 = *(const unsigned*)(hs + (long)s2 * 128 + c0);
    unsigned h3 = *(const unsigned*)(hs + (long)s3 * 128 + c0);
    float wl0 = (lane < 32) ? w0.x : w0.y;
    float wl1 = (j + 1 < end) ? ((lane < 32) ? w1.x : w1.y) : 0.f;
    float wl2 = (j + 2 < end) ? ((lane < 32) ? w2.x : w2.y) : 0.f;
    float wl3 = (j + 3 < end) ? ((lane < 32) ? w3.x : w3.y) : 0.f;
    a0 += wl0 * b2f((unsigned short)(h0 & 0xffffu)) + wl1 * b2f((unsigned short)(h1 & 0xffffu))
        + wl2 * b2f((unsigned short)(h2 & 0xffffu)) + wl3 * b2f((unsigned short)(h3 & 0xffffu));
    a1 += wl0 * b2f((unsigned short)(h0 >> 16)) + wl1 * b2f((unsigned short)(h1 >> 16))
        + wl2 * b2f((unsigned short)(h2 >> 16)) + wl3 * b2f((unsigned short)(h3 >> 16));
  }
  float2 iv2 = inv[seg];
  float iv = (lane < 32) ? iv2.x : iv2.y;
  o0 += a0 * iv; o1 += a1 * iv;
}

__global__ __launch_bounds__(256) void wallet_agg(const int* __restrict__ rowptr, const int* __restrict__ adj,
    const float2* __restrict__ alf, const float2* __restrict__ inv,
    const ushort_t* __restrict__ hs1, const ushort_t* __restrict__ hs2,
    const void* __restrict__ bsrc, ushort_t* __restrict__ out, const int* __restrict__ mode){
  int fm = mode[1];
  int d = blockIdx.x * 4 + (threadIdx.x >> 6);
  if (d >= NW) return;
  int lane = threadIdx.x & 63;
  int c0 = lane << 1;
  float o0 = 0.f, o1 = 0.f;
  conv_gather(rowptr, adj, alf, inv, NT + d,      hs1, lane, c0, o0, o1);
  conv_gather(rowptr, adj, alf, inv, NT + NW + d, hs2, lane, c0, o0, o1);
  o0 += ldf(bsrc, 128 + c0, fm)     + ldf(bsrc, 256 + c0, fm);      // b[1] + b[2] rows
  o1 += ldf(bsrc, 128 + c0 + 1, fm) + ldf(bsrc, 256 + c0 + 1, fm);
  o0 = o0 > 0.f ? o0 : expm1f(o0);
  o1 = o1 > 0.f ? o1 : expm1f(o1);
  unsigned pack = (unsigned)f2b(o0) | ((unsigned)f2b(o1) << 16);
  *(unsigned*)(out + (long)d * 128 + c0) = pack;
}

__global__ __launch_bounds__(256) void token_agg(const int* __restrict__ rowptr, const int* __restrict__ adj,
    const float2* __restrict__ alf, const float2* __restrict__ inv, const ushort_t* __restrict__ hs0,
    const void* __restrict__ bsrc, ushort_t* __restrict__ out, const int* __restrict__ mode){
  int fm = mode[1];
  int d = blockIdx.x * 4 + (threadIdx.x >> 6);
  if (d >= NT) return;
  int lane = threadIdx.x & 63;
  int c0 = lane << 1;
  float o0 = 0.f, o1 = 0.f;
  conv_gather(rowptr, adj, alf, inv, d, hs0, lane, c0, o0, o1);
  o0 += ldf(bsrc, c0, fm);          // b[0] row
  o1 += ldf(bsrc, c0 + 1, fm);
  o0 = o0 > 0.f ? o0 : expm1f(o0);
  o1 = o1 > 0.f ? o1 : expm1f(o1);
  unsigned pack = (unsigned)f2b(o0) | ((unsigned)f2b(o1) << 16);
  *(unsigned*)(out + (long)d * 128 + c0) = pack;
}

// ---------------- classifier (dtype-aware weights + output) ----------------
__global__ __launch_bounds__(256) void cls_kern(const ushort_t* __restrict__ xw, const ushort_t* __restrict__ xt,
    const void* __restrict__ Ww, const void* __restrict__ bw,
    const void* __restrict__ Wt, const void* __restrict__ bt, void* __restrict__ out,
    const int* __restrict__ mode){
  int fm = mode[1];
  int g = blockIdx.x * 4 + (threadIdx.x >> 6);
  if (g >= NW + NT) return;
  int lane = threadIdx.x & 63;
  const ushort_t* x; const void* W; const void* b;
  if (g < NW){ x = xw + (long)g * 128; W = Ww; b = bw; }
  else { x = xt + (long)(g - NW) * 128; W = Wt; b = bt; }
  unsigned xv = *(const unsigned*)(x + 2 * lane);
  float x0 = b2f((unsigned short)(xv & 0xffffu)), x1 = b2f((unsigned short)(xv >> 16));
  float w00 = ldf(W, 4 * lane + 0, fm), w01 = ldf(W, 4 * lane + 1, fm);
  float w10 = ldf(W, 4 * lane + 2, fm), w11 = ldf(W, 4 * lane + 3, fm);
  float p0 = x0 * w00 + x1 * w10;
  float p1 = x0 * w01 + x1 * w11;
#pragma unroll
  for (int off = 32; off > 0; off >>= 1){ p0 += __shfl_xor(p0, off, 64); p1 += __shfl_xor(p1, off, 64); }
  if (lane == 0){
    float r0 = p0 + ldf(b, 0, fm);
    float r1 = p1 + ldf(b, 1, fm);
    if (fm){
      ((float*)out)[(long)g * 2]     = r0;
      ((float*)out)[(long)g * 2 + 1] = r1;
    } else {
      ((ushort_t*)out)[(long)g * 2]     = f2b(r0);
      ((ushort_t*)out)[(long)g * 2 + 1] = f2b(r1);
    }
  }
}

extern "C" void kernel_launch(void* const* d_in, const int* in_sizes, int n_in,
                              void* d_out, int out_size, void* d_ws, size_t ws_size,
                              hipStream_t stream){
  const void* x_wallet = d_in[0];
  const void* x_token  = d_in[1];
  const void* lin_w_W  = d_in[2];
  const void* lin_w_b  = d_in[3];
  const void* lin_t_W  = d_in[4];
  const void* lin_t_b  = d_in[5];
  const void* Wsrc0    = d_in[6];
  const void* Wdst0    = d_in[7];
  const void* atts0    = d_in[8];
  const void* attd0    = d_in[9];
  const void* b0       = d_in[10];
  const void* Wsrc1    = d_in[11];
  const void* Wdst1    = d_in[12];
  const void* atts1    = d_in[13];
  const void* attd1    = d_in[14];
  const void* b1       = d_in[15];
  const void* cls_w_W  = d_in[16];
  const void* cls_w_b  = d_in[17];
  const void* cls_t_W  = d_in[18];
  const void* cls_t_b  = d_in[19];
  const int* e_wt = (const int*)d_in[20];
  const int* e_tw = (const int*)d_in[21];
  const int* e_ww = (const int*)d_in[22];

  char* ws = (char*)d_ws;
  size_t off = 0;
  auto alloc = [&](size_t bytes) -> char* {
    char* p = ws + off; off += (bytes + 255) & ~(size_t)255; return p;
  };
  int* rowptr = (int*)alloc((size_t)(NSEG + 1) * 4);
  int* deg    = (int*)alloc((size_t)(NSEG + 1) * 4);   // doubles as fill cursor after scan
  int* adj    = (int*)alloc((size_t)3 * EE * 4);
  float2* alf = (float2*)alloc((size_t)3 * EE * 8);
  float2* inv = (float2*)alloc((size_t)NSEG * 8);
  int* sums   = (int*)alloc(512 * 4);
  int* mode   = (int*)alloc(8);
  ushort_t* BtLw = (ushort_t*)alloc(64 * 128 * 2);
  ushort_t* BtLt = (ushort_t*)alloc(64 * 64 * 2);
  ushort_t* BtS0 = (ushort_t*)alloc(3 * 128 * 64 * 2);
  ushort_t* BtS1 = (ushort_t*)alloc(3 * 128 * 128 * 2);
  float* Uw0 = (float*)alloc(64 * 8 * 4);
  float* Ut0 = (float*)alloc(64 * 4 * 4);
  float* Uw1 = (float*)alloc(128 * 8 * 4);
  float* Ut1 = (float*)alloc(128 * 4 * 4);
  float* aw = (float*)alloc((size_t)NW * 8 * 4);
  float* at = (float*)alloc((size_t)NT * 4 * 4);
  ushort_t* hs0 = (ushort_t*)alloc((size_t)NW * 128 * 2);
  ushort_t* hs1 = (ushort_t*)alloc((size_t)NT * 128 * 2);
  ushort_t* hs2 = (ushort_t*)alloc((size_t)NW * 128 * 2);
  ushort_t* xbuf = (ushort_t*)alloc(((size_t)NW + NT) * 128 * 2);
  ushort_t* xw0 = xbuf;
  ushort_t* xt0 = xbuf + (size_t)NW * 64;
  ushort_t* xwB = xbuf;                         // aliases xw0+xt0 (both dead by then)
  ushort_t* xtB = xbuf + (size_t)NW * 128;      // disjoint from xw0/xt0
  (void)in_sizes; (void)n_in;

  if (off > ws_size){
    hipMemsetAsync(d_out, 0, (size_t)out_size * 2, stream);
    return;
  }

  hipMemsetAsync(deg, 0, (size_t)NSEG * 4, stream);
  detect_kern<<<1, 64, 0, stream>>>(e_wt, e_tw, e_ww, (const unsigned*)x_wallet, mode);

  TDesc8 td;
  td.d[0] = { lin_w_W, BtLw, 0, 128, 64 };
  td.d[1] = { lin_t_W, BtLt, 0, 64, 64 };
  for (int t = 0; t < 3; ++t){
    td.d[2 + t] = { Wsrc0, BtS0 + t * 128 * 64,  (long)t * 64 * 128,  64,  128 };
    td.d[5 + t] = { Wsrc1, BtS1 + t * 128 * 128, (long)t * 128 * 128, 128, 128 };
  }
  transpose8<<<512, 256, 0, stream>>>(td, mode);
  uprep<<<9, 256, 0, stream>>>(Wsrc0, Wdst0, atts0, attd0, Wsrc1, Wdst1, atts1, attd1, Uw0, Ut0, Uw1, Ut1, mode);

  int egrid = (3 * EE + 255) / 256;
  hist_kern<<<egrid, 256, 0, stream>>>(e_wt, e_tw, e_ww, mode, deg);
  int nch = (NSEG + 1023) / 1024;
  scan1<<<nch, 512, 0, stream>>>(deg, rowptr, sums);
  scan2<<<1, 512, 0, stream>>>(sums, nch);
  scan3<<<(NSEG + 255) / 256, 256, 0, stream>>>(rowptr, deg, sums);   // deg becomes cursor
  fill_kern<<<egrid, 256, 0, stream>>>(e_wt, e_tw, e_ww, mode, deg, adj);

  const int G = 512;
  int ncW = (NW + 127) / 128, ncT = (NT + 127) / 128;
  int sgrid = (NSEG + 255) / 256;

  // input projections (external A, dtype per mode[1])
  gemm_kern<128, 64, true, true><<<G, 256, 0, stream>>>(x_wallet, BtLw, lin_w_b, xw0, NW, mode, ncW);
  gemm_kern<64, 64, true, true><<<G, 256, 0, stream>>>(x_token, BtLt, lin_t_b, xt0, NT, mode, ncT);

  // ---- layer 0 (K=64) ----
  a_kern<64, 8><<<(NW + 255) / 256, 256, 0, stream>>>(xw0, Uw0, aw, NW);
  a_kern<64, 4><<<(NT + 255) / 256, 256, 0, stream>>>(xt0, Ut0, at, NT);
  node_softmax<<<sgrid, 256, 0, stream>>>(rowptr, adj, aw, at, alf, inv);
  gemm_kern<64, 128, false, false><<<G, 256, 0, stream>>>(xw0, BtS0, nullptr, hs0, NW, mode, ncW);
  gemm_kern<64, 128, false, false><<<G, 256, 0, stream>>>(xt0, BtS0 + 128 * 64, nullptr, hs1, NT, mode, ncT);
  gemm_kern<64, 128, false, false><<<G, 256, 0, stream>>>(xw0, BtS0 + 2 * 128 * 64, nullptr, hs2, NW, mode, ncW);
  token_agg<<<NT / 4, 256, 0, stream>>>(rowptr, adj, alf, inv, hs0, b0, xtB, mode);
  wallet_agg<<<NW / 4, 256, 0, stream>>>(rowptr, adj, alf, inv, hs1, hs2, b0, xwB, mode);

  // ---- layer 1 (K=128) ----
  a_kern<128, 8><<<(NW + 255) / 256, 256, 0, stream>>>(xwB, Uw1, aw, NW);
  a_kern<128, 4><<<(NT + 255) / 256, 256, 0, stream>>>(xtB, Ut1, at, NT);
  node_softmax<<<sgrid, 256, 0, stream>>>(rowptr, adj, aw, at, alf, inv);
  gemm_kern<128, 128, false, false><<<G, 256, 0, stream>>>(xwB, BtS1, nullptr, hs0, NW, mode, ncW);
  gemm_kern<128, 128, false, false><<<G, 256, 0, stream>>>(xtB, BtS1 + 128 * 128, nullptr, hs1, NT, mode, ncT);
  gemm_kern<128, 128, false, false><<<G, 256, 0, stream>>>(xwB, BtS1 + 2 * 128 * 128, nullptr, hs2, NW, mode, ncW);
  wallet_agg<<<NW / 4, 256, 0, stream>>>(rowptr, adj, alf, inv, hs1, hs2, b1, xwB, mode);
  token_agg<<<NT / 4, 256, 0, stream>>>(rowptr, adj, alf, inv, hs0, b1, xtB, mode);

  // classifier (dtype-aware output)
  cls_kern<<<(NW + NT) / 4, 256, 0, stream>>>(xwB, xtB, cls_w_W, cls_w_b, cls_t_W, cls_t_b, d_out, mode);
}

// Round 7
// 976.842 us; speedup vs baseline: 1.6091x; 1.1477x over previous
//
#include <hip/hip_runtime.h>
#include <stdint.h>

typedef unsigned short ushort_t;
typedef short s8v __attribute__((ext_vector_type(8)));
typedef float f4v __attribute__((ext_vector_type(4)));

#define NW 200000
#define NT 100000
#define EE 500000
#define NSEG (NT + NW + NW)   // concatenated dst slots: [tok(e_wt) | wal(e_tw) | wal(e_ww)]

__device__ __forceinline__ float b2f(unsigned short u){
  union { unsigned int i; float f; } v; v.i = ((unsigned int)u) << 16; return v.f;
}
__device__ __forceinline__ unsigned short f2b(float f){
  unsigned int x = __float_as_uint(f);
  unsigned int r = x + 0x7fffu + ((x >> 16) & 1u);   // RNE
  return (unsigned short)(r >> 16);
}
__device__ __forceinline__ float ldf(const void* p, long idx, int fm){
  return fm ? ((const float*)p)[idx] : b2f(((const ushort_t*)p)[idx]);
}

// ---------------- runtime dtype probes ----------------
// mode[0]: 1 = edges are int64, 0 = int32 ; mode[1]: 1 = floats are fp32, 0 = bf16
__global__ void detect_kern(const int* ewt, const int* etw, const int* eww,
                            const unsigned* xw_words, int* mode){
  if (threadIdx.x == 0 && blockIdx.x == 0){
    unsigned o = 0;
    for (int i = 0; i < 64; ++i)
      o |= (unsigned)ewt[2 * i + 1] | (unsigned)etw[2 * i + 1] | (unsigned)eww[2 * i + 1];
    mode[0] = (o == 0) ? 1 : 0;
    int viol = 0;
    for (int i = 0; i < 256; ++i){
      unsigned s = xw_words[i] & 0xffffu;
      unsigned e = (s >> 7) & 0xffu;
      if (!(s == 0u || s == 0x8000u || (e >= 90u && e <= 140u))) viol++;
    }
    mode[1] = (viol > 8) ? 1 : 0;
  }
}

// ------ batched weight transpose+convert: dst[n*K+k] = bf16(src[ebase + k*N + n]) ------
struct TDesc { const void* src; ushort_t* dst; long ebase; int K; int N; };
struct TDesc8 { TDesc d[8]; };
__global__ void transpose8(TDesc8 td, const int* mode){
  int fm = mode[1];
  int mi = blockIdx.x >> 6;
  TDesc t = td.d[mi];
  int e = ((blockIdx.x & 63) << 8) + threadIdx.x;
  if (e < t.K * t.N){
    int k = e / t.N, n = e - k * t.N;
    t.dst[n * t.K + k] = f2b(ldf(t.src, t.ebase + e, fm));
  }
}

// ---------------- fold att vectors into U matvec weights ----------------
// wallet cols j: 0,1=a_s type0 (h0,h1); 2,3=a_s type2; 4,5=a_d type1; 6,7=a_d type2
// token  cols jj: 0,1=a_s type1; 2,3=a_d type0
__global__ void uprep(const void* Wsrc0, const void* Wdst0, const void* atts0, const void* attd0,
                      const void* Wsrc1, const void* Wdst1, const void* atts1, const void* attd1,
                      float* Uw0, float* Ut0, float* Uw1, float* Ut1, const int* mode){
  int fm = mode[1];
  int id = blockIdx.x * 256 + threadIdx.x;
  if (id >= (64 + 128) * 12) return;
  int layer = (id >= 64 * 12);
  int rem = layer ? id - 64 * 12 : id;
  int K = layer ? 128 : 64;
  int k = rem / 12, j = rem % 12;
  const void* Ws = layer ? Wsrc1 : Wsrc0;
  const void* Wd = layer ? Wdst1 : Wdst0;
  const void* As = layer ? atts1 : atts0;
  const void* Ad = layer ? attd1 : attd0;
  int t, h; bool src;
  if (j < 8){ const int tt[8] = {0,0,2,2,1,1,2,2}; t = tt[j]; h = j & 1; src = (j < 4); }
  else { int jj = j - 8; t = (jj < 2) ? 1 : 0; h = jj & 1; src = (jj < 2); }
  const void* W = src ? Ws : Wd;
  const void* A = src ? As : Ad;
  float acc = 0.f;
  for (int c = 0; c < 64; ++c)
    acc += ldf(W, (long)(t * K + k) * 128 + h * 64 + c, fm) * ldf(A, t * 128 + h * 64 + c, fm);
  if (j < 8) (layer ? Uw1 : Uw0)[k * 8 + j] = acc;
  else       (layer ? Ut1 : Ut0)[k * 4 + (j - 8)] = acc;
}

// ---------------- CSR build ----------------
__global__ void hist_kern(const int* ewt, const int* etw, const int* eww, const int* mode, int* deg){
  int i = blockIdx.x * 256 + threadIdx.x;
  if (i >= 3 * EE) return;
  int md = mode[0];
  int t = i / EE, e = i - t * EE;
  const int* ep = (t == 0) ? ewt : (t == 1) ? etw : eww;
  int d = md ? ep[2 * (EE + e)] : ep[EE + e];
  int base = (t == 0) ? 0 : (t == 1) ? NT : NT + NW;
  atomicAdd(&deg[base + d], 1);
}

__global__ __launch_bounds__(512) void scan1(const int* deg, int* excl, int* sums){
  __shared__ int pair[512];
  int t = threadIdx.x;
  int base = blockIdx.x * 1024;
  int i0 = base + 2 * t;
  int a = (i0 < NSEG) ? deg[i0] : 0;
  int b = (i0 + 1 < NSEG) ? deg[i0 + 1] : 0;
  int ps = a + b;
  pair[t] = ps;
  __syncthreads();
  for (int off = 1; off < 512; off <<= 1){
    int v = (t >= off) ? pair[t - off] : 0;
    __syncthreads();
    if (t >= off) pair[t] += v;
    __syncthreads();
  }
  int epair = pair[t] - ps;
  if (i0 < NSEG) excl[i0] = epair;
  if (i0 + 1 < NSEG) excl[i0 + 1] = epair + a;
  if (t == 511) sums[blockIdx.x] = pair[511];
}

__global__ __launch_bounds__(512) void scan2(int* sums, int nch){
  __shared__ int s[512];
  int t = threadIdx.x;
  int orig = (t < nch) ? sums[t] : 0;
  s[t] = orig;
  __syncthreads();
  for (int off = 1; off < 512; off <<= 1){
    int v = (t >= off) ? s[t - off] : 0;
    __syncthreads();
    if (t >= off) s[t] += v;
    __syncthreads();
  }
  if (t < nch) sums[t] = s[t] - orig;
}

__global__ void scan3(int* rowptr, int* cursor, const int* sums){
  int i = blockIdx.x * 256 + threadIdx.x;
  if (i < NSEG){
    int v = rowptr[i] + sums[i >> 10];
    rowptr[i] = v; cursor[i] = v;
  }
  if (i == 0) rowptr[NSEG] = 3 * EE;
}

__global__ void fill_kern(const int* ewt, const int* etw, const int* eww, const int* mode,
                          int* cursor, int* adj){
  int i = blockIdx.x * 256 + threadIdx.x;
  if (i >= 3 * EE) return;
  int md = mode[0];
  int t = i / EE, e = i - t * EE;
  const int* ep = (t == 0) ? ewt : (t == 1) ? etw : eww;
  int s = md ? ep[2 * e] : ep[e];
  int d = md ? ep[2 * (EE + e)] : ep[EE + e];
  int base = (t == 0) ? 0 : (t == 1) ? NT : NT + NW;
  int pos = atomicAdd(&cursor[base + d], 1);
  adj[pos] = s;
}

// -------- B-stationary MFMA GEMM: C[M,NC] = A[M,K] @ Bt^T, Bt is [NC][K] bf16 --------
template<int K, int NC, bool BIAS, bool EXTA>
__global__ __launch_bounds__(256, 2) void gemm_kern(const void* __restrict__ A, const ushort_t* __restrict__ Bt,
    const void* __restrict__ bias, ushort_t* __restrict__ C, int M,
    const int* __restrict__ mode, int nchunk){
  constexpr int CT = NC / 16, KK = K / 32;
  int fm = EXTA ? mode[1] : 0;
  int tid = threadIdx.x, lane = tid & 63, wave = tid >> 6;
  int rl = lane & 15, kq = (lane >> 4) * 8;
  s8v bfrag[CT][KK];
#pragma unroll
  for (int ct = 0; ct < CT; ++ct)
#pragma unroll
    for (int kk = 0; kk < KK; ++kk)
      bfrag[ct][kk] = *(const s8v*)(Bt + (long)(ct * 16 + rl) * K + kk * 32 + kq);
  float biasv[CT];
  if (BIAS){
#pragma unroll
    for (int ct = 0; ct < CT; ++ct) biasv[ct] = ldf(bias, ct * 16 + rl, fm);
  }
  for (int chunk = blockIdx.x; chunk < nchunk; chunk += gridDim.x){
    long m0 = (long)chunk * 128 + wave * 32;
    f4v acc[2][CT];
#pragma unroll
    for (int rt = 0; rt < 2; ++rt)
#pragma unroll
      for (int ct = 0; ct < CT; ++ct) acc[rt][ct] = (f4v){0.f, 0.f, 0.f, 0.f};
#pragma unroll
    for (int rt = 0; rt < 2; ++rt){
      long row = m0 + rt * 16 + rl;
      bool ok = row < (long)M;
#pragma unroll
      for (int kk = 0; kk < KK; ++kk){
        s8v a = (s8v){0,0,0,0,0,0,0,0};
        if (ok){
          long e = row * K + kk * 32 + kq;
          if (EXTA && fm){
            const float* p = (const float*)A + e;
            uint4 lo = *(const uint4*)p;
            uint4 hi = *(const uint4*)(p + 4);
            union { s8v v; unsigned u[4]; } t;
            t.u[0] = (unsigned)f2b(__uint_as_float(lo.x)) | ((unsigned)f2b(__uint_as_float(lo.y)) << 16);
            t.u[1] = (unsigned)f2b(__uint_as_float(lo.z)) | ((unsigned)f2b(__uint_as_float(lo.w)) << 16);
            t.u[2] = (unsigned)f2b(__uint_as_float(hi.x)) | ((unsigned)f2b(__uint_as_float(hi.y)) << 16);
            t.u[3] = (unsigned)f2b(__uint_as_float(hi.z)) | ((unsigned)f2b(__uint_as_float(hi.w)) << 16);
            a = t.v;
          } else {
            a = *(const s8v*)((const ushort_t*)A + e);
          }
        }
#pragma unroll
        for (int ct = 0; ct < CT; ++ct)
          acc[rt][ct] = __builtin_amdgcn_mfma_f32_16x16x32_bf16(a, bfrag[ct][kk], acc[rt][ct], 0, 0, 0);
      }
    }
#pragma unroll
    for (int rt = 0; rt < 2; ++rt){
      long rbase = (long)chunk * 128 + wave * 32 + rt * 16 + (lane >> 4) * 4;
#pragma unroll
      for (int ct = 0; ct < CT; ++ct){
#pragma unroll
        for (int r = 0; r < 4; ++r){
          long gm = rbase + r;
          if (gm < (long)M){
            float v = acc[rt][ct][r];
            if (BIAS) v += biasv[ct];
            C[gm * NC + ct * 16 + rl] = f2b(v);
          }
        }
      }
    }
  }
}

// ------- per-node attention scalars, thread-per-node: out[N,NCOL] = x[N,K] @ U -------
template<int K, int NCOL>
__global__ __launch_bounds__(256) void a_kern(const ushort_t* __restrict__ x, const float* __restrict__ U,
                                              float* __restrict__ out, int N){
  int n = blockIdx.x * 256 + threadIdx.x;
  if (n >= N) return;
  float acc[NCOL];
#pragma unroll
  for (int j = 0; j < NCOL; ++j) acc[j] = 0.f;
  const ushort_t* xr = x + (long)n * K;
#pragma unroll
  for (int k8 = 0; k8 < K / 8; ++k8){
    uint4 v = *(const uint4*)(xr + k8 * 8);
    unsigned uu[4] = {v.x, v.y, v.z, v.w};
#pragma unroll
    for (int i = 0; i < 4; ++i){
      float f0 = b2f((unsigned short)(uu[i] & 0xffffu));
      float f1 = b2f((unsigned short)(uu[i] >> 16));
      const float* Ur = U + (k8 * 8 + i * 2) * NCOL;
#pragma unroll
      for (int j = 0; j < NCOL; ++j) acc[j] += f0 * Ur[j] + f1 * Ur[NCOL + j];
    }
  }
  f4v* o4 = (f4v*)(out + (long)n * NCOL);
#pragma unroll
  for (int q = 0; q < NCOL / 4; ++q){
    f4v t = {acc[q * 4], acc[q * 4 + 1], acc[q * 4 + 2], acc[q * 4 + 3]};
    o4[q] = t;
  }
}

// ------- fused per-node softmax (thread per dst slot), batch-4 pipelined -------
__global__ __launch_bounds__(256) void node_softmax(const int* __restrict__ rowptr,
    const int* __restrict__ adj, const float* __restrict__ aw, const float* __restrict__ at,
    float2* __restrict__ alf, float2* __restrict__ inv){
  int seg = blockIdx.x * 256 + threadIdx.x;
  if (seg >= NSEG) return;
  int beg = rowptr[seg], end = rowptr[seg + 1];
  if (beg >= end){ inv[seg] = make_float2(0.f, 0.f); return; }
  const float* asrc; int stride, col; float2 ad;
  if (seg < NT){            // type0: wallet -> token
    asrc = aw; stride = 8; col = 0;
    ad = *(const float2*)(at + (long)seg * 4 + 2);
  } else if (seg < NT + NW){ // type1: token -> wallet
    asrc = at; stride = 4; col = 0;
    ad = *(const float2*)(aw + (long)(seg - NT) * 8 + 4);
  } else {                  // type2: wallet -> wallet
    asrc = aw; stride = 8; col = 2;
    ad = *(const float2*)(aw + (long)(seg - NT - NW) * 8 + 6);
  }
  float m0 = -1e30f, m1 = -1e30f;
  for (int j = beg; j < end; j += 4){
    int j1 = min(j + 1, end - 1), j2 = min(j + 2, end - 1), j3 = min(j + 3, end - 1);
    int s0 = adj[j], s1 = adj[j1], s2 = adj[j2], s3 = adj[j3];
    float2 x0 = *(const float2*)(asrc + (long)s0 * stride + col);
    float2 x1 = *(const float2*)(asrc + (long)s1 * stride + col);
    float2 x2 = *(const float2*)(asrc + (long)s2 * stride + col);
    float2 x3 = *(const float2*)(asrc + (long)s3 * stride + col);
    float2 a0, a1, a2, a3;
    a0.x = x0.x + ad.x; a0.y = x0.y + ad.y;
    a1.x = x1.x + ad.x; a1.y = x1.y + ad.y;
    a2.x = x2.x + ad.x; a2.y = x2.y + ad.y;
    a3.x = x3.x + ad.x; a3.y = x3.y + ad.y;
    a0.x = a0.x > 0.f ? a0.x : 0.2f * a0.x;  a0.y = a0.y > 0.f ? a0.y : 0.2f * a0.y;
    a1.x = a1.x > 0.f ? a1.x : 0.2f * a1.x;  a1.y = a1.y > 0.f ? a1.y : 0.2f * a1.y;
    a2.x = a2.x > 0.f ? a2.x : 0.2f * a2.x;  a2.y = a2.y > 0.f ? a2.y : 0.2f * a2.y;
    a3.x = a3.x > 0.f ? a3.x : 0.2f * a3.x;  a3.y = a3.y > 0.f ? a3.y : 0.2f * a3.y;
    alf[j] = a0; alf[j1] = a1; alf[j2] = a2; alf[j3] = a3;   // idempotent duplicates
    m0 = fmaxf(fmaxf(m0, fmaxf(a0.x, a1.x)), fmaxf(a2.x, a3.x));
    m1 = fmaxf(fmaxf(m1, fmaxf(a0.y, a1.y)), fmaxf(a2.y, a3.y));
  }
  float d0 = 0.f, d1 = 0.f;
  for (int j = beg; j < end; j += 4){
    int j1 = min(j + 1, end - 1), j2 = min(j + 2, end - 1), j3 = min(j + 3, end - 1);
    float2 a0 = alf[j], a1 = alf[j1], a2 = alf[j2], a3 = alf[j3];
    a0.x = __expf(a0.x - m0); a0.y = __expf(a0.y - m1);
    a1.x = __expf(a1.x - m0); a1.y = __expf(a1.y - m1);
    a2.x = __expf(a2.x - m0); a2.y = __expf(a2.y - m1);
    a3.x = __expf(a3.x - m0); a3.y = __expf(a3.y - m1);
    alf[j] = a0; alf[j1] = a1; alf[j2] = a2; alf[j3] = a3;
    bool v1 = j + 1 < end, v2 = j + 2 < end, v3 = j + 3 < end;
    d0 += a0.x + (v1 ? a1.x : 0.f) + (v2 ? a2.x : 0.f) + (v3 ? a3.x : 0.f);
    d1 += a0.y + (v1 ? a1.y : 0.f) + (v2 ? a2.y : 0.f) + (v3 ? a3.y : 0.f);
  }
  inv[seg] = make_float2(1.f / (d0 + 1e-16f), 1.f / (d1 + 1e-16f));
}

// ------- weighted gather (wave per dst node), scalar-uniform control, batch-4 -------
// seg/beg/end/adj/alf/inv are wave-uniform -> SALU + s_load; only hs rows are vector loads.
__device__ __forceinline__ void conv_gather(const int* __restrict__ rowptr, const int* __restrict__ adj,
    const float2* __restrict__ alf, const float2* __restrict__ inv, int seg,
    const ushort_t* __restrict__ hs, int lane, int c0, float& o0, float& o1){
  int beg = rowptr[seg], end = rowptr[seg + 1];
  if (beg >= end) return;
  float a0 = 0.f, a1 = 0.f;
  for (int j = beg; j < end; j += 4){
    int j1 = min(j + 1, end - 1), j2 = min(j + 2, end - 1), j3 = min(j + 3, end - 1);
    int s0 = adj[j], s1 = adj[j1], s2 = adj[j2], s3 = adj[j3];
    float2 w0 = alf[j], w1 = alf[j1], w2 = alf[j2], w3 = alf[j3];
    unsigned h0 = *(const unsigned*)(hs + (long)s0 * 128 + c0);   // saddr-form, 256B/wave
    unsigned h1 = *(const unsigned*)(hs + (long)s1 * 128 + c0);
    unsigned h2 = *(const unsigned*)(hs + (long)s2 * 128 + c0);
    unsigned h3 = *(const unsigned*)(hs + (long)s3 * 128 + c0);
    float wl0 = (lane < 32) ? w0.x : w0.y;
    float wl1 = (j + 1 < end) ? ((lane < 32) ? w1.x : w1.y) : 0.f;
    float wl2 = (j + 2 < end) ? ((lane < 32) ? w2.x : w2.y) : 0.f;
    float wl3 = (j + 3 < end) ? ((lane < 32) ? w3.x : w3.y) : 0.f;
    a0 += wl0 * b2f((unsigned short)(h0 & 0xffffu)) + wl1 * b2f((unsigned short)(h1 & 0xffffu))
        + wl2 * b2f((unsigned short)(h2 & 0xffffu)) + wl3 * b2f((unsigned short)(h3 & 0xffffu));
    a1 += wl0 * b2f((unsigned short)(h0 >> 16)) + wl1 * b2f((unsigned short)(h1 >> 16))
        + wl2 * b2f((unsigned short)(h2 >> 16)) + wl3 * b2f((unsigned short)(h3 >> 16));
  }
  float2 iv2 = inv[seg];
  float iv = (lane < 32) ? iv2.x : iv2.y;
  o0 += a0 * iv; o1 += a1 * iv;
}

// FINAL: fuse classifier (layer-1 outputs feed ONLY cls) -> write 2 logits, skip 256B row.
template<bool FINAL>
__global__ __launch_bounds__(256) void wallet_agg(const int* __restrict__ rowptr, const int* __restrict__ adj,
    const float2* __restrict__ alf, const float2* __restrict__ inv,
    const ushort_t* __restrict__ hs1, const ushort_t* __restrict__ hs2,
    const void* __restrict__ bsrc, ushort_t* __restrict__ out,
    const void* __restrict__ clsW, const void* __restrict__ clsb, void* __restrict__ dout,
    const int* __restrict__ mode){
  int fm = mode[1];
  int d = blockIdx.x * 4 + __builtin_amdgcn_readfirstlane(threadIdx.x >> 6);  // wave-uniform
  if (d >= NW) return;
  int lane = threadIdx.x & 63;
  int c0 = lane << 1;
  float o0 = 0.f, o1 = 0.f;
  conv_gather(rowptr, adj, alf, inv, NT + d,      hs1, lane, c0, o0, o1);
  conv_gather(rowptr, adj, alf, inv, NT + NW + d, hs2, lane, c0, o0, o1);
  o0 += ldf(bsrc, 128 + c0, fm)     + ldf(bsrc, 256 + c0, fm);      // b[1] + b[2] rows
  o1 += ldf(bsrc, 128 + c0 + 1, fm) + ldf(bsrc, 256 + c0 + 1, fm);
  o0 = o0 > 0.f ? o0 : expm1f(o0);
  o1 = o1 > 0.f ? o1 : expm1f(o1);
  if (!FINAL){
    unsigned pack = (unsigned)f2b(o0) | ((unsigned)f2b(o1) << 16);
    *(unsigned*)(out + (long)d * 128 + c0) = pack;
  } else {
    float w00 = ldf(clsW, 4 * lane + 0, fm), w01 = ldf(clsW, 4 * lane + 1, fm);
    float w10 = ldf(clsW, 4 * lane + 2, fm), w11 = ldf(clsW, 4 * lane + 3, fm);
    float p0 = o0 * w00 + o1 * w10;
    float p1 = o0 * w01 + o1 * w11;
#pragma unroll
    for (int off = 32; off > 0; off >>= 1){ p0 += __shfl_xor(p0, off, 64); p1 += __shfl_xor(p1, off, 64); }
    if (lane == 0){
      float r0 = p0 + ldf(clsb, 0, fm);
      float r1 = p1 + ldf(clsb, 1, fm);
      if (fm){ ((float*)dout)[(long)d * 2] = r0; ((float*)dout)[(long)d * 2 + 1] = r1; }
      else { ((ushort_t*)dout)[(long)d * 2] = f2b(r0); ((ushort_t*)dout)[(long)d * 2 + 1] = f2b(r1); }
    }
  }
}

template<bool FINAL>
__global__ __launch_bounds__(256) void token_agg(const int* __restrict__ rowptr, const int* __restrict__ adj,
    const float2* __restrict__ alf, const float2* __restrict__ inv, const ushort_t* __restrict__ hs0,
    const void* __restrict__ bsrc, ushort_t* __restrict__ out,
    const void* __restrict__ clsW, const void* __restrict__ clsb, void* __restrict__ dout,
    const int* __restrict__ mode){
  int fm = mode[1];
  int d = blockIdx.x * 4 + __builtin_amdgcn_readfirstlane(threadIdx.x >> 6);  // wave-uniform
  if (d >= NT) return;
  int lane = threadIdx.x & 63;
  int c0 = lane << 1;
  float o0 = 0.f, o1 = 0.f;
  conv_gather(rowptr, adj, alf, inv, d, hs0, lane, c0, o0, o1);
  o0 += ldf(bsrc, c0, fm);          // b[0] row
  o1 += ldf(bsrc, c0 + 1, fm);
  o0 = o0 > 0.f ? o0 : expm1f(o0);
  o1 = o1 > 0.f ? o1 : expm1f(o1);
  if (!FINAL){
    unsigned pack = (unsigned)f2b(o0) | ((unsigned)f2b(o1) << 16);
    *(unsigned*)(out + (long)d * 128 + c0) = pack;
  } else {
    float w00 = ldf(clsW, 4 * lane + 0, fm), w01 = ldf(clsW, 4 * lane + 1, fm);
    float w10 = ldf(clsW, 4 * lane + 2, fm), w11 = ldf(clsW, 4 * lane + 3, fm);
    float p0 = o0 * w00 + o1 * w10;
    float p1 = o0 * w01 + o1 * w11;
#pragma unroll
    for (int off = 32; off > 0; off >>= 1){ p0 += __shfl_xor(p0, off, 64); p1 += __shfl_xor(p1, off, 64); }
    if (lane == 0){
      long g = (long)NW + d;
      float r0 = p0 + ldf(clsb, 0, fm);
      float r1 = p1 + ldf(clsb, 1, fm);
      if (fm){ ((float*)dout)[g * 2] = r0; ((float*)dout)[g * 2 + 1] = r1; }
      else { ((ushort_t*)dout)[g * 2] = f2b(r0); ((ushort_t*)dout)[g * 2 + 1] = f2b(r1); }
    }
  }
}

extern "C" void kernel_launch(void* const* d_in, const int* in_sizes, int n_in,
                              void* d_out, int out_size, void* d_ws, size_t ws_size,
                              hipStream_t stream){
  const void* x_wallet = d_in[0];
  const void* x_token  = d_in[1];
  const void* lin_w_W  = d_in[2];
  const void* lin_w_b  = d_in[3];
  const void* lin_t_W  = d_in[4];
  const void* lin_t_b  = d_in[5];
  const void* Wsrc0    = d_in[6];
  const void* Wdst0    = d_in[7];
  const void* atts0    = d_in[8];
  const void* attd0    = d_in[9];
  const void* b0       = d_in[10];
  const void* Wsrc1    = d_in[11];
  const void* Wdst1    = d_in[12];
  const void* atts1    = d_in[13];
  const void* attd1    = d_in[14];
  const void* b1       = d_in[15];
  const void* cls_w_W  = d_in[16];
  const void* cls_w_b  = d_in[17];
  const void* cls_t_W  = d_in[18];
  const void* cls_t_b  = d_in[19];
  const int* e_wt = (const int*)d_in[20];
  const int* e_tw = (const int*)d_in[21];
  const int* e_ww = (const int*)d_in[22];

  char* ws = (char*)d_ws;
  size_t off = 0;
  auto alloc = [&](size_t bytes) -> char* {
    char* p = ws + off; off += (bytes + 255) & ~(size_t)255; return p;
  };
  int* rowptr = (int*)alloc((size_t)(NSEG + 1) * 4);
  int* deg    = (int*)alloc((size_t)(NSEG + 1) * 4);   // doubles as fill cursor after scan
  int* adj    = (int*)alloc((size_t)3 * EE * 4);
  float2* alf = (float2*)alloc((size_t)3 * EE * 8);
  float2* inv = (float2*)alloc((size_t)NSEG * 8);
  int* sums   = (int*)alloc(512 * 4);
  int* mode   = (int*)alloc(8);
  ushort_t* BtLw = (ushort_t*)alloc(64 * 128 * 2);
  ushort_t* BtLt = (ushort_t*)alloc(64 * 64 * 2);
  ushort_t* BtS0 = (ushort_t*)alloc(3 * 128 * 64 * 2);
  ushort_t* BtS1 = (ushort_t*)alloc(3 * 128 * 128 * 2);
  float* Uw0 = (float*)alloc(64 * 8 * 4);
  float* Ut0 = (float*)alloc(64 * 4 * 4);
  float* Uw1 = (float*)alloc(128 * 8 * 4);
  float* Ut1 = (float*)alloc(128 * 4 * 4);
  float* aw = (float*)alloc((size_t)NW * 8 * 4);
  float* at = (float*)alloc((size_t)NT * 4 * 4);
  ushort_t* hs0 = (ushort_t*)alloc((size_t)NW * 128 * 2);
  ushort_t* hs1 = (ushort_t*)alloc((size_t)NT * 128 * 2);
  ushort_t* hs2 = (ushort_t*)alloc((size_t)NW * 128 * 2);
  ushort_t* xbuf = (ushort_t*)alloc(((size_t)NW + NT) * 128 * 2);
  ushort_t* xw0 = xbuf;
  ushort_t* xt0 = xbuf + (size_t)NW * 64;
  ushort_t* xwB = xbuf;                         // aliases xw0+xt0 (both dead by then)
  ushort_t* xtB = xbuf + (size_t)NW * 128;      // disjoint from xw0/xt0
  (void)in_sizes; (void)n_in;

  if (off > ws_size){
    hipMemsetAsync(d_out, 0, (size_t)out_size * 2, stream);
    return;
  }

  hipMemsetAsync(deg, 0, (size_t)NSEG * 4, stream);
  detect_kern<<<1, 64, 0, stream>>>(e_wt, e_tw, e_ww, (const unsigned*)x_wallet, mode);

  TDesc8 td;
  td.d[0] = { lin_w_W, BtLw, 0, 128, 64 };
  td.d[1] = { lin_t_W, BtLt, 0, 64, 64 };
  for (int t = 0; t < 3; ++t){
    td.d[2 + t] = { Wsrc0, BtS0 + t * 128 * 64,  (long)t * 64 * 128,  64,  128 };
    td.d[5 + t] = { Wsrc1, BtS1 + t * 128 * 128, (long)t * 128 * 128, 128, 128 };
  }
  transpose8<<<512, 256, 0, stream>>>(td, mode);
  uprep<<<9, 256, 0, stream>>>(Wsrc0, Wdst0, atts0, attd0, Wsrc1, Wdst1, atts1, attd1, Uw0, Ut0, Uw1, Ut1, mode);

  int egrid = (3 * EE + 255) / 256;
  hist_kern<<<egrid, 256, 0, stream>>>(e_wt, e_tw, e_ww, mode, deg);
  int nch = (NSEG + 1023) / 1024;
  scan1<<<nch, 512, 0, stream>>>(deg, rowptr, sums);
  scan2<<<1, 512, 0, stream>>>(sums, nch);
  scan3<<<(NSEG + 255) / 256, 256, 0, stream>>>(rowptr, deg, sums);   // deg becomes cursor
  fill_kern<<<egrid, 256, 0, stream>>>(e_wt, e_tw, e_ww, mode, deg, adj);

  const int G = 512;
  int ncW = (NW + 127) / 128, ncT = (NT + 127) / 128;
  int sgrid = (NSEG + 255) / 256;

  // input projections (external A, dtype per mode[1])
  gemm_kern<128, 64, true, true><<<G, 256, 0, stream>>>(x_wallet, BtLw, lin_w_b, xw0, NW, mode, ncW);
  gemm_kern<64, 64, true, true><<<G, 256, 0, stream>>>(x_token, BtLt, lin_t_b, xt0, NT, mode, ncT);

  // ---- layer 0 (K=64) ----
  a_kern<64, 8><<<(NW + 255) / 256, 256, 0, stream>>>(xw0, Uw0, aw, NW);
  a_kern<64, 4><<<(NT + 255) / 256, 256, 0, stream>>>(xt0, Ut0, at, NT);
  node_softmax<<<sgrid, 256, 0, stream>>>(rowptr, adj, aw, at, alf, inv);
  gemm_kern<64, 128, false, false><<<G, 256, 0, stream>>>(xw0, BtS0, nullptr, hs0, NW, mode, ncW);
  gemm_kern<64, 128, false, false><<<G, 256, 0, stream>>>(xt0, BtS0 + 128 * 64, nullptr, hs1, NT, mode, ncT);
  gemm_kern<64, 128, false, false><<<G, 256, 0, stream>>>(xw0, BtS0 + 2 * 128 * 64, nullptr, hs2, NW, mode, ncW);
  token_agg<false><<<NT / 4, 256, 0, stream>>>(rowptr, adj, alf, inv, hs0, b0, xtB, nullptr, nullptr, nullptr, mode);
  wallet_agg<false><<<NW / 4, 256, 0, stream>>>(rowptr, adj, alf, inv, hs1, hs2, b0, xwB, nullptr, nullptr, nullptr, mode);

  // ---- layer 1 (K=128), classifier fused into agg ----
  a_kern<128, 8><<<(NW + 255) / 256, 256, 0, stream>>>(xwB, Uw1, aw, NW);
  a_kern<128, 4><<<(NT + 255) / 256, 256, 0, stream>>>(xtB, Ut1, at, NT);
  node_softmax<<<sgrid, 256, 0, stream>>>(rowptr, adj, aw, at, alf, inv);
  gemm_kern<128, 128, false, false><<<G, 256, 0, stream>>>(xwB, BtS1, nullptr, hs0, NW, mode, ncW);
  gemm_kern<128, 128, false, false><<<G, 256, 0, stream>>>(xtB, BtS1 + 128 * 128, nullptr, hs1, NT, mode, ncT);
  gemm_kern<128, 128, false, false><<<G, 256, 0, stream>>>(xwB, BtS1 + 2 * 128 * 128, nullptr, hs2, NW, mode, ncW);
  wallet_agg<true><<<NW / 4, 256, 0, stream>>>(rowptr, adj, alf, inv, hs1, hs2, b1, nullptr, cls_w_W, cls_w_b, d_out, mode);
  token_agg<true><<<NT / 4, 256, 0, stream>>>(rowptr, adj, alf, inv, hs0, b1, nullptr, cls_t_W, cls_t_b, d_out, mode);
}

// Round 8
// 949.799 us; speedup vs baseline: 1.6549x; 1.0285x over previous
//
#include <hip/hip_runtime.h>
#include <stdint.h>

typedef unsigned short ushort_t;
typedef short s8v __attribute__((ext_vector_type(8)));
typedef float f4v __attribute__((ext_vector_type(4)));

#define NW 200000
#define NT 100000
#define EE 500000
#define NSEG (NT + NW + NW)   // concatenated dst slots: [tok(e_wt) | wal(e_tw) | wal(e_ww)]

__device__ __forceinline__ float b2f(unsigned short u){
  union { unsigned int i; float f; } v; v.i = ((unsigned int)u) << 16; return v.f;
}
__device__ __forceinline__ unsigned short f2b(float f){
  unsigned int x = __float_as_uint(f);
  unsigned int r = x + 0x7fffu + ((x >> 16) & 1u);   // RNE
  return (unsigned short)(r >> 16);
}
__device__ __forceinline__ float ldf(const void* p, long idx, int fm){
  return fm ? ((const float*)p)[idx] : b2f(((const ushort_t*)p)[idx]);
}

// ---------------- runtime dtype probes ----------------
// mode[0]: 1 = edges are int64, 0 = int32 ; mode[1]: 1 = floats are fp32, 0 = bf16
__global__ void detect_kern(const int* ewt, const int* etw, const int* eww,
                            const unsigned* xw_words, int* mode){
  if (threadIdx.x == 0 && blockIdx.x == 0){
    unsigned o = 0;
    for (int i = 0; i < 64; ++i)
      o |= (unsigned)ewt[2 * i + 1] | (unsigned)etw[2 * i + 1] | (unsigned)eww[2 * i + 1];
    mode[0] = (o == 0) ? 1 : 0;
    int viol = 0;
    for (int i = 0; i < 256; ++i){
      unsigned s = xw_words[i] & 0xffffu;
      unsigned e = (s >> 7) & 0xffu;
      if (!(s == 0u || s == 0x8000u || (e >= 90u && e <= 140u))) viol++;
    }
    mode[1] = (viol > 8) ? 1 : 0;
  }
}

// ------ batched weight transpose+convert: dst[n*K+k] = bf16(src[ebase + k*N + n]) ------
struct TDesc { const void* src; ushort_t* dst; long ebase; int K; int N; };
struct TDesc8 { TDesc d[8]; };
__global__ void transpose8(TDesc8 td, const int* mode){
  int fm = mode[1];
  int mi = blockIdx.x >> 6;
  TDesc t = td.d[mi];
  int e = ((blockIdx.x & 63) << 8) + threadIdx.x;
  if (e < t.K * t.N){
    int k = e / t.N, n = e - k * t.N;
    t.dst[n * t.K + k] = f2b(ldf(t.src, t.ebase + e, fm));
  }
}

// ---------------- fold att vectors into U matvec weights ----------------
// wallet cols j: 0,1=a_s type0 (h0,h1); 2,3=a_s type2; 4,5=a_d type1; 6,7=a_d type2
// token  cols jj: 0,1=a_s type1; 2,3=a_d type0
__global__ void uprep(const void* Wsrc0, const void* Wdst0, const void* atts0, const void* attd0,
                      const void* Wsrc1, const void* Wdst1, const void* atts1, const void* attd1,
                      float* Uw0, float* Ut0, float* Uw1, float* Ut1, const int* mode){
  int fm = mode[1];
  int id = blockIdx.x * 256 + threadIdx.x;
  if (id >= (64 + 128) * 12) return;
  int layer = (id >= 64 * 12);
  int rem = layer ? id - 64 * 12 : id;
  int K = layer ? 128 : 64;
  int k = rem / 12, j = rem % 12;
  const void* Ws = layer ? Wsrc1 : Wsrc0;
  const void* Wd = layer ? Wdst1 : Wdst0;
  const void* As = layer ? atts1 : atts0;
  const void* Ad = layer ? attd1 : attd0;
  int t, h; bool src;
  if (j < 8){ const int tt[8] = {0,0,2,2,1,1,2,2}; t = tt[j]; h = j & 1; src = (j < 4); }
  else { int jj = j - 8; t = (jj < 2) ? 1 : 0; h = jj & 1; src = (jj < 2); }
  const void* W = src ? Ws : Wd;
  const void* A = src ? As : Ad;
  float acc = 0.f;
  for (int c = 0; c < 64; ++c)
    acc += ldf(W, (long)(t * K + k) * 128 + h * 64 + c, fm) * ldf(A, t * 128 + h * 64 + c, fm);
  if (j < 8) (layer ? Uw1 : Uw0)[k * 8 + j] = acc;
  else       (layer ? Ut1 : Ut0)[k * 4 + (j - 8)] = acc;
}

// ---------------- CSR build ----------------
__global__ void hist_kern(const int* ewt, const int* etw, const int* eww, const int* mode, int* deg){
  int i = blockIdx.x * 256 + threadIdx.x;
  if (i >= 3 * EE) return;
  int md = mode[0];
  int t = i / EE, e = i - t * EE;
  const int* ep = (t == 0) ? ewt : (t == 1) ? etw : eww;
  int d = md ? ep[2 * (EE + e)] : ep[EE + e];
  int base = (t == 0) ? 0 : (t == 1) ? NT : NT + NW;
  atomicAdd(&deg[base + d], 1);
}

__global__ __launch_bounds__(512) void scan1(const int* deg, int* excl, int* sums){
  __shared__ int pair[512];
  int t = threadIdx.x;
  int base = blockIdx.x * 1024;
  int i0 = base + 2 * t;
  int a = (i0 < NSEG) ? deg[i0] : 0;
  int b = (i0 + 1 < NSEG) ? deg[i0 + 1] : 0;
  int ps = a + b;
  pair[t] = ps;
  __syncthreads();
  for (int off = 1; off < 512; off <<= 1){
    int v = (t >= off) ? pair[t - off] : 0;
    __syncthreads();
    if (t >= off) pair[t] += v;
    __syncthreads();
  }
  int epair = pair[t] - ps;
  if (i0 < NSEG) excl[i0] = epair;
  if (i0 + 1 < NSEG) excl[i0 + 1] = epair + a;
  if (t == 511) sums[blockIdx.x] = pair[511];
}

__global__ __launch_bounds__(512) void scan2(int* sums, int nch){
  __shared__ int s[512];
  int t = threadIdx.x;
  int orig = (t < nch) ? sums[t] : 0;
  s[t] = orig;
  __syncthreads();
  for (int off = 1; off < 512; off <<= 1){
    int v = (t >= off) ? s[t - off] : 0;
    __syncthreads();
    if (t >= off) s[t] += v;
    __syncthreads();
  }
  if (t < nch) sums[t] = s[t] - orig;
}

__global__ void scan3(int* rowptr, int* cursor, const int* sums){
  int i = blockIdx.x * 256 + threadIdx.x;
  if (i < NSEG){
    int v = rowptr[i] + sums[i >> 10];
    rowptr[i] = v; cursor[i] = v;
  }
  if (i == 0) rowptr[NSEG] = 3 * EE;
}

__global__ void fill_kern(const int* ewt, const int* etw, const int* eww, const int* mode,
                          int* cursor, int* adj){
  int i = blockIdx.x * 256 + threadIdx.x;
  if (i >= 3 * EE) return;
  int md = mode[0];
  int t = i / EE, e = i - t * EE;
  const int* ep = (t == 0) ? ewt : (t == 1) ? etw : eww;
  int s = md ? ep[2 * e] : ep[e];
  int d = md ? ep[2 * (EE + e)] : ep[EE + e];
  int base = (t == 0) ? 0 : (t == 1) ? NT : NT + NW;
  int pos = atomicAdd(&cursor[base + d], 1);
  adj[pos] = s;
}

// -------- B-stationary MFMA GEMM: C[M,NC] = A[M,K] @ Bt^T, Bt is [NC][K] bf16 --------
template<int K, int NC, bool BIAS, bool EXTA>
__global__ __launch_bounds__(256, 2) void gemm_kern(const void* __restrict__ A, const ushort_t* __restrict__ Bt,
    const void* __restrict__ bias, ushort_t* __restrict__ C, int M,
    const int* __restrict__ mode, int nchunk){
  constexpr int CT = NC / 16, KK = K / 32;
  int fm = EXTA ? mode[1] : 0;
  int tid = threadIdx.x, lane = tid & 63, wave = tid >> 6;
  int rl = lane & 15, kq = (lane >> 4) * 8;
  s8v bfrag[CT][KK];
#pragma unroll
  for (int ct = 0; ct < CT; ++ct)
#pragma unroll
    for (int kk = 0; kk < KK; ++kk)
      bfrag[ct][kk] = *(const s8v*)(Bt + (long)(ct * 16 + rl) * K + kk * 32 + kq);
  float biasv[CT];
  if (BIAS){
#pragma unroll
    for (int ct = 0; ct < CT; ++ct) biasv[ct] = ldf(bias, ct * 16 + rl, fm);
  }
  for (int chunk = blockIdx.x; chunk < nchunk; chunk += gridDim.x){
    long m0 = (long)chunk * 128 + wave * 32;
    f4v acc[2][CT];
#pragma unroll
    for (int rt = 0; rt < 2; ++rt)
#pragma unroll
      for (int ct = 0; ct < CT; ++ct) acc[rt][ct] = (f4v){0.f, 0.f, 0.f, 0.f};
#pragma unroll
    for (int rt = 0; rt < 2; ++rt){
      long row = m0 + rt * 16 + rl;
      bool ok = row < (long)M;
#pragma unroll
      for (int kk = 0; kk < KK; ++kk){
        s8v a = (s8v){0,0,0,0,0,0,0,0};
        if (ok){
          long e = row * K + kk * 32 + kq;
          if (EXTA && fm){
            const float* p = (const float*)A + e;
            uint4 lo = *(const uint4*)p;
            uint4 hi = *(const uint4*)(p + 4);
            union { s8v v; unsigned u[4]; } t;
            t.u[0] = (unsigned)f2b(__uint_as_float(lo.x)) | ((unsigned)f2b(__uint_as_float(lo.y)) << 16);
            t.u[1] = (unsigned)f2b(__uint_as_float(lo.z)) | ((unsigned)f2b(__uint_as_float(lo.w)) << 16);
            t.u[2] = (unsigned)f2b(__uint_as_float(hi.x)) | ((unsigned)f2b(__uint_as_float(hi.y)) << 16);
            t.u[3] = (unsigned)f2b(__uint_as_float(hi.z)) | ((unsigned)f2b(__uint_as_float(hi.w)) << 16);
            a = t.v;
          } else {
            a = *(const s8v*)((const ushort_t*)A + e);
          }
        }
#pragma unroll
        for (int ct = 0; ct < CT; ++ct)
          acc[rt][ct] = __builtin_amdgcn_mfma_f32_16x16x32_bf16(a, bfrag[ct][kk], acc[rt][ct], 0, 0, 0);
      }
    }
#pragma unroll
    for (int rt = 0; rt < 2; ++rt){
      long rbase = (long)chunk * 128 + wave * 32 + rt * 16 + (lane >> 4) * 4;
#pragma unroll
      for (int ct = 0; ct < CT; ++ct){
#pragma unroll
        for (int r = 0; r < 4; ++r){
          long gm = rbase + r;
          if (gm < (long)M){
            float v = acc[rt][ct][r];
            if (BIAS) v += biasv[ct];
            C[gm * NC + ct * 16 + rl] = f2b(v);
          }
        }
      }
    }
  }
}

// ------- per-node attention scalars, thread-per-node: out[N,NCOL] = x[N,K] @ U -------
template<int K, int NCOL>
__global__ __launch_bounds__(256) void a_kern(const ushort_t* __restrict__ x, const float* __restrict__ U,
                                              float* __restrict__ out, int N){
  int n = blockIdx.x * 256 + threadIdx.x;
  if (n >= N) return;
  float acc[NCOL];
#pragma unroll
  for (int j = 0; j < NCOL; ++j) acc[j] = 0.f;
  const ushort_t* xr = x + (long)n * K;
#pragma unroll
  for (int k8 = 0; k8 < K / 8; ++k8){
    uint4 v = *(const uint4*)(xr + k8 * 8);
    unsigned uu[4] = {v.x, v.y, v.z, v.w};
#pragma unroll
    for (int i = 0; i < 4; ++i){
      float f0 = b2f((unsigned short)(uu[i] & 0xffffu));
      float f1 = b2f((unsigned short)(uu[i] >> 16));
      const float* Ur = U + (k8 * 8 + i * 2) * NCOL;
#pragma unroll
      for (int j = 0; j < NCOL; ++j) acc[j] += f0 * Ur[j] + f1 * Ur[NCOL + j];
    }
  }
  f4v* o4 = (f4v*)(out + (long)n * NCOL);
#pragma unroll
  for (int q = 0; q < NCOL / 4; ++q){
    f4v t = {acc[q * 4], acc[q * 4 + 1], acc[q * 4 + 2], acc[q * 4 + 3]};
    o4[q] = t;
  }
}

// ------- per-node softmax, single-pass register-buffered (deg<=8), writes NORMALIZED weights -------
__global__ __launch_bounds__(256) void node_softmax(const int* __restrict__ rowptr,
    const int* __restrict__ adj, const float* __restrict__ aw, const float* __restrict__ at,
    float2* __restrict__ alf){
  int seg = blockIdx.x * 256 + threadIdx.x;
  if (seg >= NSEG) return;
  int beg = rowptr[seg], end = rowptr[seg + 1];
  int n = end - beg;
  if (n <= 0) return;
  const float* asrc; int stride, col; float2 ad;
  if (seg < NT){            // type0: wallet -> token
    asrc = aw; stride = 8; col = 0;
    ad = *(const float2*)(at + (long)seg * 4 + 2);
  } else if (seg < NT + NW){ // type1: token -> wallet
    asrc = at; stride = 4; col = 0;
    ad = *(const float2*)(aw + (long)(seg - NT) * 8 + 4);
  } else {                  // type2: wallet -> wallet
    asrc = aw; stride = 8; col = 2;
    ad = *(const float2*)(aw + (long)(seg - NT - NW) * 8 + 6);
  }
  if (n <= 8){
    float2 buf[8];
    float m0 = -1e30f, m1 = -1e30f;
#pragma unroll
    for (int i = 0; i < 8; ++i){
      if (i < n){
        int s = adj[beg + i];
        float2 x = *(const float2*)(asrc + (long)s * stride + col);
        float a0 = x.x + ad.x, a1 = x.y + ad.y;
        a0 = a0 > 0.f ? a0 : 0.2f * a0;
        a1 = a1 > 0.f ? a1 : 0.2f * a1;
        buf[i] = make_float2(a0, a1);
        m0 = fmaxf(m0, a0); m1 = fmaxf(m1, a1);
      }
    }
    float d0 = 0.f, d1 = 0.f;
#pragma unroll
    for (int i = 0; i < 8; ++i){
      if (i < n){
        float w0 = __expf(buf[i].x - m0), w1 = __expf(buf[i].y - m1);
        d0 += w0; d1 += w1;
        buf[i] = make_float2(w0, w1);
      }
    }
    float i0 = 1.f / (d0 + 1e-16f), i1 = 1.f / (d1 + 1e-16f);
#pragma unroll
    for (int i = 0; i < 8; ++i)
      if (i < n) alf[beg + i] = make_float2(buf[i].x * i0, buf[i].y * i1);
  } else {
    // rare long-degree fallback: 3 passes
    float m0 = -1e30f, m1 = -1e30f;
    for (int j = beg; j < end; ++j){
      int s = adj[j];
      float2 x = *(const float2*)(asrc + (long)s * stride + col);
      float a0 = x.x + ad.x, a1 = x.y + ad.y;
      a0 = a0 > 0.f ? a0 : 0.2f * a0;
      a1 = a1 > 0.f ? a1 : 0.2f * a1;
      alf[j] = make_float2(a0, a1);
      m0 = fmaxf(m0, a0); m1 = fmaxf(m1, a1);
    }
    float d0 = 0.f, d1 = 0.f;
    for (int j = beg; j < end; ++j){
      float2 a = alf[j];
      a.x = __expf(a.x - m0); a.y = __expf(a.y - m1);
      d0 += a.x; d1 += a.y;
      alf[j] = a;
    }
    float i0 = 1.f / (d0 + 1e-16f), i1 = 1.f / (d1 + 1e-16f);
    for (int j = beg; j < end; ++j){
      float2 a = alf[j];
      alf[j] = make_float2(a.x * i0, a.y * i1);
    }
  }
}

// ------- weighted gather (wave per dst node), scalar-uniform control, batch-4 -------
__device__ __forceinline__ void conv_gather(const int* __restrict__ rowptr, const int* __restrict__ adj,
    const float2* __restrict__ alf, int seg, const ushort_t* __restrict__ hs,
    int lane, int c0, float& o0, float& o1){
  int beg = rowptr[seg], end = rowptr[seg + 1];
  if (beg >= end) return;
  for (int j = beg; j < end; j += 4){
    int j1 = min(j + 1, end - 1), j2 = min(j + 2, end - 1), j3 = min(j + 3, end - 1);
    int s0 = adj[j], s1 = adj[j1], s2 = adj[j2], s3 = adj[j3];
    float2 w0 = alf[j], w1 = alf[j1], w2 = alf[j2], w3 = alf[j3];
    unsigned h0 = *(const unsigned*)(hs + (long)s0 * 128 + c0);   // 256B/wave coalesced
    unsigned h1 = *(const unsigned*)(hs + (long)s1 * 128 + c0);
    unsigned h2 = *(const unsigned*)(hs + (long)s2 * 128 + c0);
    unsigned h3 = *(const unsigned*)(hs + (long)s3 * 128 + c0);
    float wl0 = (lane < 32) ? w0.x : w0.y;
    float wl1 = (j + 1 < end) ? ((lane < 32) ? w1.x : w1.y) : 0.f;
    float wl2 = (j + 2 < end) ? ((lane < 32) ? w2.x : w2.y) : 0.f;
    float wl3 = (j + 3 < end) ? ((lane < 32) ? w3.x : w3.y) : 0.f;
    o0 += wl0 * b2f((unsigned short)(h0 & 0xffffu)) + wl1 * b2f((unsigned short)(h1 & 0xffffu))
        + wl2 * b2f((unsigned short)(h2 & 0xffffu)) + wl3 * b2f((unsigned short)(h3 & 0xffffu));
    o1 += wl0 * b2f((unsigned short)(h0 >> 16)) + wl1 * b2f((unsigned short)(h1 >> 16))
        + wl2 * b2f((unsigned short)(h2 >> 16)) + wl3 * b2f((unsigned short)(h3 >> 16));
  }
}

// ------- merged agg: blocks [0,NT/4) = token nodes, rest = wallet nodes -------
// FINAL: classifier fused, writes 2 logits/node instead of 256B hidden row.
template<bool FINAL>
__global__ __launch_bounds__(256) void agg_all(const int* __restrict__ rowptr, const int* __restrict__ adj,
    const float2* __restrict__ alf,
    const ushort_t* __restrict__ hs0, const ushort_t* __restrict__ hs1, const ushort_t* __restrict__ hs2,
    const void* __restrict__ bsrc, ushort_t* __restrict__ xt_out, ushort_t* __restrict__ xw_out,
    const void* __restrict__ clsWw, const void* __restrict__ clsbw,
    const void* __restrict__ clsWt, const void* __restrict__ clsbt,
    void* __restrict__ dout, const int* __restrict__ mode){
  int fm = mode[1];
  int wv = __builtin_amdgcn_readfirstlane(threadIdx.x >> 6);  // wave-uniform
  int lane = threadIdx.x & 63;
  int c0 = lane << 1;
  int bid = blockIdx.x;
  const int TB = NT / 4;
  float o0 = 0.f, o1 = 0.f;
  bool is_tok = bid < TB;
  int d;
  if (is_tok){
    d = bid * 4 + wv;
    conv_gather(rowptr, adj, alf, d, hs0, lane, c0, o0, o1);
    o0 += ldf(bsrc, c0, fm);
    o1 += ldf(bsrc, c0 + 1, fm);
  } else {
    d = (bid - TB) * 4 + wv;
    conv_gather(rowptr, adj, alf, NT + d,      hs1, lane, c0, o0, o1);
    conv_gather(rowptr, adj, alf, NT + NW + d, hs2, lane, c0, o0, o1);
    o0 += ldf(bsrc, 128 + c0, fm)     + ldf(bsrc, 256 + c0, fm);
    o1 += ldf(bsrc, 128 + c0 + 1, fm) + ldf(bsrc, 256 + c0 + 1, fm);
  }
  o0 = o0 > 0.f ? o0 : __expf(o0) - 1.f;   // ELU (2-ulp exp fine under bf16 rounding)
  o1 = o1 > 0.f ? o1 : __expf(o1) - 1.f;
  if (!FINAL){
    ushort_t* out = is_tok ? xt_out : xw_out;
    unsigned pack = (unsigned)f2b(o0) | ((unsigned)f2b(o1) << 16);
    *(unsigned*)(out + (long)d * 128 + c0) = pack;
  } else {
    const void* W = is_tok ? clsWt : clsWw;
    const void* b = is_tok ? clsbt : clsbw;
    float w00 = ldf(W, 4 * lane + 0, fm), w01 = ldf(W, 4 * lane + 1, fm);
    float w10 = ldf(W, 4 * lane + 2, fm), w11 = ldf(W, 4 * lane + 3, fm);
    float p0 = o0 * w00 + o1 * w10;
    float p1 = o0 * w01 + o1 * w11;
#pragma unroll
    for (int off = 32; off > 0; off >>= 1){ p0 += __shfl_xor(p0, off, 64); p1 += __shfl_xor(p1, off, 64); }
    if (lane == 0){
      long g = is_tok ? (long)NW + d : (long)d;
      float r0 = p0 + ldf(b, 0, fm);
      float r1 = p1 + ldf(b, 1, fm);
      if (fm){ ((float*)dout)[g * 2] = r0; ((float*)dout)[g * 2 + 1] = r1; }
      else { ((ushort_t*)dout)[g * 2] = f2b(r0); ((ushort_t*)dout)[g * 2 + 1] = f2b(r1); }
    }
  }
}

extern "C" void kernel_launch(void* const* d_in, const int* in_sizes, int n_in,
                              void* d_out, int out_size, void* d_ws, size_t ws_size,
                              hipStream_t stream){
  const void* x_wallet = d_in[0];
  const void* x_token  = d_in[1];
  const void* lin_w_W  = d_in[2];
  const void* lin_w_b  = d_in[3];
  const void* lin_t_W  = d_in[4];
  const void* lin_t_b  = d_in[5];
  const void* Wsrc0    = d_in[6];
  const void* Wdst0    = d_in[7];
  const void* atts0    = d_in[8];
  const void* attd0    = d_in[9];
  const void* b0       = d_in[10];
  const void* Wsrc1    = d_in[11];
  const void* Wdst1    = d_in[12];
  const void* atts1    = d_in[13];
  const void* attd1    = d_in[14];
  const void* b1       = d_in[15];
  const void* cls_w_W  = d_in[16];
  const void* cls_w_b  = d_in[17];
  const void* cls_t_W  = d_in[18];
  const void* cls_t_b  = d_in[19];
  const int* e_wt = (const int*)d_in[20];
  const int* e_tw = (const int*)d_in[21];
  const int* e_ww = (const int*)d_in[22];

  char* ws = (char*)d_ws;
  size_t off = 0;
  auto alloc = [&](size_t bytes) -> char* {
    char* p = ws + off; off += (bytes + 255) & ~(size_t)255; return p;
  };
  int* rowptr = (int*)alloc((size_t)(NSEG + 1) * 4);
  int* deg    = (int*)alloc((size_t)(NSEG + 1) * 4);   // doubles as fill cursor after scan
  int* adj    = (int*)alloc((size_t)3 * EE * 4);
  float2* alf = (float2*)alloc((size_t)3 * EE * 8);
  int* sums   = (int*)alloc(512 * 4);
  int* mode   = (int*)alloc(8);
  ushort_t* BtLw = (ushort_t*)alloc(64 * 128 * 2);
  ushort_t* BtLt = (ushort_t*)alloc(64 * 64 * 2);
  ushort_t* BtS0 = (ushort_t*)alloc(3 * 128 * 64 * 2);
  ushort_t* BtS1 = (ushort_t*)alloc(3 * 128 * 128 * 2);
  float* Uw0 = (float*)alloc(64 * 8 * 4);
  float* Ut0 = (float*)alloc(64 * 4 * 4);
  float* Uw1 = (float*)alloc(128 * 8 * 4);
  float* Ut1 = (float*)alloc(128 * 4 * 4);
  float* aw = (float*)alloc((size_t)NW * 8 * 4);
  float* at = (float*)alloc((size_t)NT * 4 * 4);
  ushort_t* hs0 = (ushort_t*)alloc((size_t)NW * 128 * 2);
  ushort_t* hs1 = (ushort_t*)alloc((size_t)NT * 128 * 2);
  ushort_t* hs2 = (ushort_t*)alloc((size_t)NW * 128 * 2);
  ushort_t* xbuf = (ushort_t*)alloc(((size_t)NW + NT) * 128 * 2);
  ushort_t* xw0 = xbuf;
  ushort_t* xt0 = xbuf + (size_t)NW * 64;
  ushort_t* xwB = xbuf;                         // aliases xw0+xt0 (both dead by then)
  ushort_t* xtB = xbuf + (size_t)NW * 128;      // disjoint from xw0/xt0
  (void)in_sizes; (void)n_in;

  if (off > ws_size){
    hipMemsetAsync(d_out, 0, (size_t)out_size * 2, stream);
    return;
  }

  hipMemsetAsync(deg, 0, (size_t)NSEG * 4, stream);
  detect_kern<<<1, 64, 0, stream>>>(e_wt, e_tw, e_ww, (const unsigned*)x_wallet, mode);

  TDesc8 td;
  td.d[0] = { lin_w_W, BtLw, 0, 128, 64 };
  td.d[1] = { lin_t_W, BtLt, 0, 64, 64 };
  for (int t = 0; t < 3; ++t){
    td.d[2 + t] = { Wsrc0, BtS0 + t * 128 * 64,  (long)t * 64 * 128,  64,  128 };
    td.d[5 + t] = { Wsrc1, BtS1 + t * 128 * 128, (long)t * 128 * 128, 128, 128 };
  }
  transpose8<<<512, 256, 0, stream>>>(td, mode);
  uprep<<<9, 256, 0, stream>>>(Wsrc0, Wdst0, atts0, attd0, Wsrc1, Wdst1, atts1, attd1, Uw0, Ut0, Uw1, Ut1, mode);

  int egrid = (3 * EE + 255) / 256;
  hist_kern<<<egrid, 256, 0, stream>>>(e_wt, e_tw, e_ww, mode, deg);
  int nch = (NSEG + 1023) / 1024;
  scan1<<<nch, 512, 0, stream>>>(deg, rowptr, sums);
  scan2<<<1, 512, 0, stream>>>(sums, nch);
  scan3<<<(NSEG + 255) / 256, 256, 0, stream>>>(rowptr, deg, sums);   // deg becomes cursor
  fill_kern<<<egrid, 256, 0, stream>>>(e_wt, e_tw, e_ww, mode, deg, adj);

  const int G = 512;
  int ncW = (NW + 127) / 128, ncT = (NT + 127) / 128;
  int sgrid = (NSEG + 255) / 256;
  int agrid = NT / 4 + NW / 4;

  // input projections (external A, dtype per mode[1])
  gemm_kern<128, 64, true, true><<<G, 256, 0, stream>>>(x_wallet, BtLw, lin_w_b, xw0, NW, mode, ncW);
  gemm_kern<64, 64, true, true><<<G, 256, 0, stream>>>(x_token, BtLt, lin_t_b, xt0, NT, mode, ncT);

  // ---- layer 0 (K=64) ----
  a_kern<64, 8><<<(NW + 255) / 256, 256, 0, stream>>>(xw0, Uw0, aw, NW);
  a_kern<64, 4><<<(NT + 255) / 256, 256, 0, stream>>>(xt0, Ut0, at, NT);
  node_softmax<<<sgrid, 256, 0, stream>>>(rowptr, adj, aw, at, alf);
  gemm_kern<64, 128, false, false><<<G, 256, 0, stream>>>(xw0, BtS0, nullptr, hs0, NW, mode, ncW);
  gemm_kern<64, 128, false, false><<<G, 256, 0, stream>>>(xt0, BtS0 + 128 * 64, nullptr, hs1, NT, mode, ncT);
  gemm_kern<64, 128, false, false><<<G, 256, 0, stream>>>(xw0, BtS0 + 2 * 128 * 64, nullptr, hs2, NW, mode, ncW);
  agg_all<false><<<agrid, 256, 0, stream>>>(rowptr, adj, alf, hs0, hs1, hs2, b0, xtB, xwB,
                                            nullptr, nullptr, nullptr, nullptr, nullptr, mode);

  // ---- layer 1 (K=128), classifier fused ----
  a_kern<128, 8><<<(NW + 255) / 256, 256, 0, stream>>>(xwB, Uw1, aw, NW);
  a_kern<128, 4><<<(NT + 255) / 256, 256, 0, stream>>>(xtB, Ut1, at, NT);
  node_softmax<<<sgrid, 256, 0, stream>>>(rowptr, adj, aw, at, alf);
  gemm_kern<128, 128, false, false><<<G, 256, 0, stream>>>(xwB, BtS1, nullptr, hs0, NW, mode, ncW);
  gemm_kern<128, 128, false, false><<<G, 256, 0, stream>>>(xtB, BtS1 + 128 * 128, nullptr, hs1, NT, mode, ncT);
  gemm_kern<128, 128, false, false><<<G, 256, 0, stream>>>(xwB, BtS1 + 2 * 128 * 128, nullptr, hs2, NW, mode, ncW);
  agg_all<true><<<agrid, 256, 0, stream>>>(rowptr, adj, alf, hs0, hs1, hs2, b1, nullptr, nullptr,
                                           cls_w_W, cls_w_b, cls_t_W, cls_t_b, d_out, mode);
}